// Round 6
// baseline (192.806 us; speedup 1.0000x reference)
//
#include <hip/hip_runtime.h>
#include <cstdint>
#include <cmath>

typedef unsigned int uint;
typedef unsigned short ushort;
typedef __bf16 bf16_t;
typedef bf16_t bf16x8 __attribute__((ext_vector_type(8)));
typedef float f32x4 __attribute__((ext_vector_type(4)));
typedef float f32x16 __attribute__((ext_vector_type(16)));

#define LOG2E 1.44269504088896340736f

__device__ __forceinline__ ushort f2bf(float f) {
  uint x = __float_as_uint(f);
  x += 0x7fffu + ((x >> 16) & 1u);   // RNE to bf16
  return (ushort)(x >> 16);
}
__device__ __forceinline__ uint pack2(float lo, float hi) {
  return (uint)f2bf(lo) | ((uint)f2bf(hi) << 16);
}
__device__ __forceinline__ uint cvt_pk_bf16(float lo, float hi) {
  uint r;
  asm("v_cvt_pk_bf16_f32 %0, %1, %2" : "=v"(r) : "v"(lo), "v"(hi));
  return r;
}

// global -> LDS direct copy, 16B per lane; LDS dest is wave-uniform base + lane*16.
__device__ __forceinline__ void gload_lds16(const void* gsrc, void* ldsdst) {
  typedef const __attribute__((address_space(1))) unsigned int* gp_t;
  typedef __attribute__((address_space(3))) unsigned int* lp_t;
  __builtin_amdgcn_global_load_lds((gp_t)(uintptr_t)gsrc,
                                   (lp_t)(unsigned int)(uintptr_t)ldsdst,
                                   16, 0, 0);
}

// ---------------- fp32 -> bf16 converts ----------------
__global__ __launch_bounds__(256) void cvt_x(const float* __restrict__ src,
                                             ushort* __restrict__ dst, int n8) {
  int i = blockIdx.x * blockDim.x + threadIdx.x;
  if (i >= n8) return;
  const float4* s4 = (const float4*)src;
  float4 a = s4[i * 2], b = s4[i * 2 + 1];
  uint4 o;
  o.x = pack2(a.x, a.y); o.y = pack2(a.z, a.w);
  o.z = pack2(b.x, b.y); o.w = pack2(b.z, b.w);
  ((uint4*)dst)[i] = o;
}

// 4 weight matrices in one launch: y=0..2 -> Wqkvb slices, y=3 -> Wob
__global__ __launch_bounds__(256) void cvt_w4(const float* __restrict__ s0,
                                              const float* __restrict__ s1,
                                              const float* __restrict__ s2,
                                              const float* __restrict__ s3,
                                              ushort* __restrict__ dA,
                                              ushort* __restrict__ dB, int n8) {
  const int y = blockIdx.y;
  const float* src = (y == 0) ? s0 : (y == 1) ? s1 : (y == 2) ? s2 : s3;
  ushort* dst = (y < 3) ? (dA + (size_t)y * n8 * 8) : dB;
  int i = blockIdx.x * blockDim.x + threadIdx.x;
  if (i >= n8) return;
  const float4* s4 = (const float4*)src;
  float4 a = s4[i * 2], b = s4[i * 2 + 1];
  uint4 o;
  o.x = pack2(a.x, a.y); o.y = pack2(a.z, a.w);
  o.z = pack2(b.x, b.y); o.w = pack2(b.z, b.w);
  ((uint4*)dst)[i] = o;
}

// ---------------- fused QKV GEMM: 256x256 tile, BK=64, 8 waves, 4-phase counted pipeline
// Wave grid 2(M)x4(N); per-wave C = 128x64 (acc[8][4] of 16x16 frags).
// LDS: 2 K-tile buffers x (A 256x64 + B 256x64) bf16 = 128 KiB.
// Swizzle: LDS[row][chunk] = G[row][chunk ^ (row&7)] (both-sides, conflict-free b128).
// Stage of tile j+1 issued in phases 1-2 of iter j into the other buffer (race-free);
// single vmcnt(0)+raw-barrier at iteration boundary (issue-to-wait gap ~2.5 phases).
__global__ __launch_bounds__(512, 2) void gemm_qkv256(const ushort* __restrict__ A,
                                                      const ushort* __restrict__ B,
                                                      const float* __restrict__ bq,
                                                      const float* __restrict__ bk,
                                                      const float* __restrict__ bv,
                                                      float* __restrict__ qpre,
                                                      float* __restrict__ kpre,
                                                      ushort* __restrict__ Vt,
                                                      int K, int S_) {
  __shared__ __align__(16) unsigned char lds[131072];   // A: [2][32768]; B at +65536
  const int t = threadIdx.x, l = t & 63;
  const int w = t >> 6;
  const int g = l >> 4, c = l & 15;
  const int wr = w >> 2, wc = w & 3;          // 2 x 4 wave grid
  const int tm = blockIdx.y * 256, tn = blockIdx.x * 256;

  // staging: per K-tile 4 loads for A (64-row slabs) + 4 for B
  const int srow = t >> 3;                    // 0..63
  const int schunk = (t & 7) ^ (srow & 7);    // pre-swizzled source chunk
  const ushort* Ag = A + (size_t)(tm + srow) * K + schunk * 8;
  const ushort* Bg = B + (size_t)(tn + srow) * K + schunk * 8;
  const size_t rK64 = (size_t)64 * K;

#define STAGE_A(nb, kt) do { const ushort* s_ = Ag + (size_t)(kt) * 64;          \
    gload_lds16(s_,            lds + (nb) * 32768 + t * 16);                     \
    gload_lds16(s_ + rK64,     lds + (nb) * 32768 + 8192 + t * 16);              \
    gload_lds16(s_ + 2 * rK64, lds + (nb) * 32768 + 16384 + t * 16);             \
    gload_lds16(s_ + 3 * rK64, lds + (nb) * 32768 + 24576 + t * 16); } while (0)
#define STAGE_B(nb, kt) do { const ushort* s_ = Bg + (size_t)(kt) * 64;          \
    gload_lds16(s_,            lds + 65536 + (nb) * 32768 + t * 16);             \
    gload_lds16(s_ + rK64,     lds + 65536 + (nb) * 32768 + 8192 + t * 16);      \
    gload_lds16(s_ + 2 * rK64, lds + 65536 + (nb) * 32768 + 16384 + t * 16);     \
    gload_lds16(s_ + 3 * rK64, lds + 65536 + (nb) * 32768 + 24576 + t * 16); } while (0)

  f32x4 acc[8][4] = {};
  bf16x8 af[2][4], bf[2][4];

#define RD_A(QM) do {                                                            \
    _Pragma("unroll") for (int ks = 0; ks < 2; ++ks)                             \
    _Pragma("unroll") for (int mm = 0; mm < 4; ++mm) {                           \
      int rh = (QM) * 64 + mm * 16 + c;                                          \
      af[ks][mm] = *(const bf16x8*)(Ab + rh * 128 + (((ks * 4 + g) ^ (rh & 7)) << 4)); } \
  } while (0)
#define RD_B() do {                                                              \
    _Pragma("unroll") for (int ks = 0; ks < 2; ++ks)                             \
    _Pragma("unroll") for (int nn = 0; nn < 4; ++nn) {                           \
      int rh = (wc & 1) * 64 + nn * 16 + c;                                      \
      bf[ks][nn] = *(const bf16x8*)(Bb + rh * 128 + (((ks * 4 + g) ^ (rh & 7)) << 4)); } \
  } while (0)
#define MM16(QM, QN) do {                                                        \
    __builtin_amdgcn_s_barrier();                                                \
    __builtin_amdgcn_s_setprio(1);                                               \
    _Pragma("unroll") for (int mm = 0; mm < 4; ++mm)                             \
    _Pragma("unroll") for (int nn = 0; nn < 2; ++nn) {                           \
      acc[(QM)*4+mm][(QN)*2+nn] = __builtin_amdgcn_mfma_f32_16x16x32_bf16(       \
          af[0][mm], bf[0][(QN)*2+nn], acc[(QM)*4+mm][(QN)*2+nn], 0, 0, 0);      \
      acc[(QM)*4+mm][(QN)*2+nn] = __builtin_amdgcn_mfma_f32_16x16x32_bf16(       \
          af[1][mm], bf[1][(QN)*2+nn], acc[(QM)*4+mm][(QN)*2+nn], 0, 0, 0); }    \
    __builtin_amdgcn_s_setprio(0);                                               \
    __builtin_amdgcn_s_barrier();                                                \
  } while (0)

  const int NT = K >> 6;   // 32 K-tiles
  // prologue: stage tile 0 into buf 0
  STAGE_A(0, 0);
  STAGE_B(0, 0);
  asm volatile("s_waitcnt vmcnt(0)" ::: "memory");
  __builtin_amdgcn_s_barrier();

  for (int j = 0; j < NT; ++j) {
    const int buf = j & 1, nb = buf ^ 1;
    const unsigned char* Ab = lds + buf * 32768 + wr * 16384;
    const unsigned char* Bb = lds + 65536 + buf * 32768 + (wc >> 1) * 16384;
    const int kt1 = j + 1;
    const bool st = kt1 < NT;
    // phase 1: read A(qm0) + all B; stage next A
    RD_A(0); RD_B();
    if (st) STAGE_A(nb, kt1);
    MM16(0, 0);
    // phase 2: no reads; stage next B
    if (st) STAGE_B(nb, kt1);
    MM16(0, 1);
    // phase 3: read A(qm1)
    RD_A(1);
    MM16(1, 0);
    // phase 4
    MM16(1, 1);
    // boundary: next tile's loads must have landed before anyone reads them
    asm volatile("s_waitcnt vmcnt(0)" ::: "memory");
    __builtin_amdgcn_s_barrier();
  }

#undef STAGE_A
#undef STAGE_B
#undef RD_A
#undef RD_B
#undef MM16

  const int sel = tn >> 11;   // uniform per block (2048 % 256 == 0)
  if (sel < 2) {
    float* outp = sel ? kpre : qpre;
    const float* bias = sel ? bk : bq;
#pragma unroll
    for (int n = 0; n < 4; ++n) {
      int col = (tn & 2047) + wc * 64 + n * 16 + c;
      float bvv = bias[col];
#pragma unroll
      for (int m = 0; m < 8; ++m) {
        int row0 = tm + wr * 128 + m * 16 + g * 4;
#pragma unroll
        for (int i = 0; i < 4; ++i)
          outp[(size_t)(row0 + i) * 2048 + col] = acc[m][n][i] + bvv;
      }
    }
  } else {
#pragma unroll
    for (int n = 0; n < 4; ++n) {
      int colv = (tn - 4096) + wc * 64 + n * 16 + c;
      float bvv = bv[colv];
#pragma unroll
      for (int m = 0; m < 8; ++m) {
        int row0 = tm + wr * 128 + m * 16 + g * 4;
        uint2 o;
        o.x = pack2(acc[m][n][0] + bvv, acc[m][n][1] + bvv);
        o.y = pack2(acc[m][n][2] + bvv, acc[m][n][3] + bvv);
        *(uint2*)(Vt + (size_t)colv * S_ + row0) = o;
      }
    }
  }
}

// ---------------- Wo GEMM split-K=2, 8 waves (proven R5) -> fp32 partials ------
__global__ __launch_bounds__(512) void gemm_wo(const ushort* __restrict__ A,
                                               const ushort* __restrict__ B,
                                               float* __restrict__ pbuf, int K) {
  __shared__ __align__(16) unsigned char As[8192];
  __shared__ __align__(16) unsigned char Bs[8192];
  const int t = threadIdx.x, l = t & 63, w = t >> 6;
  const int g = l >> 4, c = l & 15;
  const int wr = w >> 1, wc = w & 1;
  const int tm = blockIdx.y * 128, tn = blockIdx.x * 128;
  const int ks = blockIdx.z;
  const int k0 = ks * (K >> 1), k1 = k0 + (K >> 1);

  const int srow = w * 16 + (l >> 2);
  const int schunk = (l & 3) ^ (srow & 3);
  const ushort* Ag = A + (size_t)(tm + srow) * K + schunk * 8;
  const ushort* Bg = B + (size_t)(tn + srow) * K + schunk * 8;
  void* AsBase = (void*)(As + w * 1024);
  void* BsBase = (void*)(Bs + w * 1024);

  f32x4 acc[2][4] = {};

  for (int kt = k0; kt < k1; kt += 32) {
    __syncthreads();
    gload_lds16(Ag + kt, AsBase);
    gload_lds16(Bg + kt, BsBase);
    __syncthreads();
    bf16x8 af[2], bfr[4];
#pragma unroll
    for (int m = 0; m < 2; ++m) {
      int row = wr * 32 + m * 16 + c;
      af[m] = *(const bf16x8*)(As + row * 64 + ((g ^ (row & 3)) << 4));
    }
#pragma unroll
    for (int n = 0; n < 4; ++n) {
      int row = wc * 64 + n * 16 + c;
      bfr[n] = *(const bf16x8*)(Bs + row * 64 + ((g ^ (row & 3)) << 4));
    }
#pragma unroll
    for (int m = 0; m < 2; ++m)
#pragma unroll
      for (int n = 0; n < 4; ++n)
        acc[m][n] = __builtin_amdgcn_mfma_f32_16x16x32_bf16(af[m], bfr[n], acc[m][n], 0, 0, 0);
  }

  float* out = pbuf + (size_t)ks * 2048 * 2048;
#pragma unroll
  for (int n = 0; n < 4; ++n) {
    int col = tn + wc * 64 + n * 16 + c;
#pragma unroll
    for (int m = 0; m < 2; ++m) {
      int row0 = tm + wr * 32 + m * 16 + g * 4;
#pragma unroll
      for (int i = 0; i < 4; ++i)
        out[(size_t)(row0 + i) * 2048 + col] = acc[m][n][i];
    }
  }
}

__global__ __launch_bounds__(256) void reduce_wo(const float* __restrict__ p,
                                                 const float* __restrict__ bo,
                                                 float* __restrict__ out, int n4) {
  int i = blockIdx.x * blockDim.x + threadIdx.x;
  if (i >= n4) return;
  float4 a = ((const float4*)p)[i];
  float4 b = ((const float4*)p)[i + n4];
  float4 bb = *(const float4*)(bo + ((i * 4) & 2047));
  float4 o;
  o.x = a.x + b.x + bb.x; o.y = a.y + b.y + bb.y;
  o.z = a.z + b.z + bb.z; o.w = a.w + b.w + bb.w;
  ((float4*)out)[i] = o;
}

// ---------------- fused rmsnorm + 3-axis RoPE + scale-fold, fp32 -> bf16 ----------------
__global__ __launch_bounds__(256) void fuse_rms_rope(const float* __restrict__ qpre,
                                                     const float* __restrict__ kpre,
                                                     const float* __restrict__ gq,
                                                     const float* __restrict__ gk,
                                                     const float* __restrict__ fc,
                                                     const float* __restrict__ fs,
                                                     const int* __restrict__ pH,
                                                     const int* __restrict__ pW,
                                                     ushort* __restrict__ Qb,
                                                     ushort* __restrict__ Kb,
                                                     int dim, float foldq) {
  const int which = blockIdx.y;
  const float* pre = which ? kpre : qpre;
  const float* gw = which ? gk : gq;
  ushort* outp = which ? Kb : Qb;
  const float fold = which ? 1.0f : foldq;

  const int p = blockIdx.x, t = threadIdx.x;
  const float* row = pre + (size_t)p * dim;
  float v[8];
  {
    float4 a = *(const float4*)(row + t * 8);
    float4 b = *(const float4*)(row + t * 8 + 4);
    v[0] = a.x; v[1] = a.y; v[2] = a.z; v[3] = a.w;
    v[4] = b.x; v[5] = b.y; v[6] = b.z; v[7] = b.w;
  }
  float ss = 0.f;
#pragma unroll
  for (int i = 0; i < 8; ++i) ss += v[i] * v[i];
#pragma unroll
  for (int off = 32; off; off >>= 1) ss += __shfl_xor(ss, off);
  __shared__ float wsum[4];
  if ((t & 63) == 0) wsum[t >> 6] = ss;
  __syncthreads();
  float rstd = rsqrtf((wsum[0] + wsum[1] + wsum[2] + wsum[3]) * (1.0f / dim) + 1e-6f);
  float gv[8];
  {
    float4 a = *(const float4*)(gw + t * 8);
    float4 b = *(const float4*)(gw + t * 8 + 4);
    gv[0] = a.x; gv[1] = a.y; gv[2] = a.z; gv[3] = a.w;
    gv[4] = b.x; gv[5] = b.y; gv[6] = b.z; gv[7] = b.w;
  }
#pragma unroll
  for (int i = 0; i < 8; ++i) v[i] = v[i] * rstd * gv[i];

  const int H = pH[0], W = pW[0];
  const int hw = H * W;
  const int fr = p / hw;
  const int rem = p - fr * hw;
  const int hh = rem / W;
  const int ww = rem - hh * W;
  const int hd = dim / 16;
  const int cd = hd >> 1;
  const int c2 = cd / 3, c1 = cd - 2 * c2;
  const int j0 = ((t * 8) % hd) >> 1;

  uint ob[4];
#pragma unroll
  for (int q = 0; q < 4; ++q) {
    int j = j0 + q;
    int ri = (j < c1) ? fr : ((j < c1 + c2) ? hh : ww);
    float cs = fc[ri * cd + j];
    float sn = fs[ri * cd + j];
    float a = v[2 * q], b = v[2 * q + 1];
    ob[q] = pack2((a * cs - b * sn) * fold, (a * sn + b * cs) * fold);
  }
  uint4 o4; o4.x = ob[0]; o4.y = ob[1]; o4.z = ob[2]; o4.w = ob[3];
  *(uint4*)(outp + (size_t)p * dim + t * 8) = o4;
}

// ---------------- flash attention, 32x32 MFMA, 4 q-subtiles x 2 KV-splits ----------------
__global__ __launch_bounds__(512, 2) void attn32(const ushort* __restrict__ Qb,
                                                 const ushort* __restrict__ Kb,
                                                 const ushort* __restrict__ Vt,
                                                 ushort* __restrict__ Ob,
                                                 const int* __restrict__ seq_lens,
                                                 int S_, int DIMc) {
  __shared__ __align__(16) unsigned char smem[66560];
  float* mlbuf = (float*)(smem + 65536);
  const int t = threadIdx.x, l = t & 63, w = t >> 6;
  const int qsub = w & 3, ksp = w >> 2;
  const int h = l >> 5, ql = l & 31;

  const int orig = blockIdx.y * gridDim.x + blockIdx.x;
  const int nwg = gridDim.x * gridDim.y;
  const int lin = (orig & 7) * (nwg >> 3) + (orig >> 3);
  const int q0 = (lin % gridDim.x) * 128;
  const int head = lin / gridDim.x;
  const int kvlen = seq_lens[0];

  unsigned char* sk_s = smem + ksp * 16384;
  unsigned char* sv_s = smem + 32768 + ksp * 16384;

  bf16x8 qf[8];
  {
    const ushort* qp = Qb + (size_t)(q0 + qsub * 32 + ql) * DIMc + head * 128 + h * 8;
#pragma unroll
    for (int s = 0; s < 8; ++s) qf[s] = *(const bf16x8*)(qp + s * 16);
  }

  f32x16 ofr[4] = {};
  float m_run = -1e30f, l_run = 0.f;

  const int nt = (kvlen + 63) >> 6;
  const int half = (nt + 1) >> 1;
  const int tbase = ksp ? half : 0;
  const int mycnt = ksp ? (nt - half) : half;

  for (int tt = 0; tt < half; ++tt) {
    __syncthreads();
    if (tt < mycnt) {
      const int kv0 = (tbase + tt) * 64;
#pragma unroll
      for (int it = 0; it < 4; ++it) {
        int kr = qsub * 16 + it * 4 + (l >> 4);
        int kc = (l & 15) ^ (kr & 15);
        gload_lds16(Kb + (size_t)(kv0 + kr) * DIMc + head * 128 + kc * 8,
                    sk_s + qsub * 4096 + it * 1024);
        int vr = qsub * 32 + it * 8 + (l >> 3);
        int vc = (l & 7) ^ (vr & 7);
        gload_lds16(Vt + (size_t)(head * 128 + vr) * S_ + kv0 + vc * 8,
                    sv_s + qsub * 4096 + it * 1024);
      }
    }
    __syncthreads();
    if (tt >= mycnt) continue;
    const int kv0 = (tbase + tt) * 64;

    f32x16 sfr[2] = {};
    __builtin_amdgcn_s_setprio(1);
#pragma unroll
    for (int kb = 0; kb < 2; ++kb) {
      const unsigned char* kbp = sk_s + (kb * 32 + ql) * 256;
      const int rx = (kb * 32 + ql) & 15;
#pragma unroll
      for (int s = 0; s < 8; ++s) {
        bf16x8 kf = *(const bf16x8*)(kbp + (((s * 2 + h) ^ rx) << 4));
        sfr[kb] = __builtin_amdgcn_mfma_f32_32x32x16_bf16(kf, qf[s], sfr[kb], 0, 0, 0);
      }
    }
    __builtin_amdgcn_s_setprio(0);

    if (kv0 + 64 > kvlen) {
#pragma unroll
      for (int kb = 0; kb < 2; ++kb)
#pragma unroll
        for (int r = 0; r < 16; ++r) {
          int key = kv0 + kb * 32 + (r & 3) + 8 * (r >> 2) + 4 * h;
          if (key >= kvlen) sfr[kb][r] = -1e30f;
        }
    }

    float mt = -1e30f;
#pragma unroll
    for (int kb = 0; kb < 2; ++kb)
#pragma unroll
      for (int r = 0; r < 16; ++r) mt = fmaxf(mt, sfr[kb][r]);
    mt = fmaxf(mt, __shfl_xor(mt, 32));

    if (!__all(mt <= m_run + 8.0f)) {
      float m_new = fmaxf(m_run, mt);
      float fac = __builtin_amdgcn_exp2f(m_run - m_new);
      l_run *= fac;
#pragma unroll
      for (int df = 0; df < 4; ++df) ofr[df] *= fac;
      m_run = m_new;
    }

    float ls = 0.f;
    uint u[2][4][2];
#pragma unroll
    for (int kb = 0; kb < 2; ++kb)
#pragma unroll
      for (int G = 0; G < 4; ++G) {
        float p0 = __builtin_amdgcn_exp2f(sfr[kb][G * 4 + 0] - m_run);
        float p1 = __builtin_amdgcn_exp2f(sfr[kb][G * 4 + 1] - m_run);
        float p2 = __builtin_amdgcn_exp2f(sfr[kb][G * 4 + 2] - m_run);
        float p3 = __builtin_amdgcn_exp2f(sfr[kb][G * 4 + 3] - m_run);
        ls += (p0 + p1) + (p2 + p3);
        u[kb][G][0] = cvt_pk_bf16(p0, p1);
        u[kb][G][1] = cvt_pk_bf16(p2, p3);
      }
    ls += __shfl_xor(ls, 32);
    l_run += ls;

#pragma unroll
    for (int ks = 0; ks < 4; ++ks) {
      const int kb = ks >> 1, G0 = (ks & 1) * 2;
      uint own0 = h ? u[kb][G0 + 1][0] : u[kb][G0][0];
      uint own1 = h ? u[kb][G0 + 1][1] : u[kb][G0][1];
      uint snd0 = h ? u[kb][G0][0] : u[kb][G0 + 1][0];
      uint snd1 = h ? u[kb][G0][1] : u[kb][G0 + 1][1];
      uint rcv0 = __shfl_xor(snd0, 32);
      uint rcv1 = __shfl_xor(snd1, 32);
      union { uint4 q; bf16x8 b; } uu;
      uu.q.x = h ? rcv0 : own0;
      uu.q.y = h ? rcv1 : own1;
      uu.q.z = h ? own0 : rcv0;
      uu.q.w = h ? own1 : rcv1;
      __builtin_amdgcn_s_setprio(1);
#pragma unroll
      for (int df = 0; df < 4; ++df) {
        const int row = df * 32 + ql;
        bf16x8 vf = *(const bf16x8*)(sv_s + row * 128 + (((ks * 2 + h) ^ (row & 7)) << 4));
        ofr[df] = __builtin_amdgcn_mfma_f32_32x32x16_bf16(vf, uu.b, ofr[df], 0, 0, 0);
      }
      __builtin_amdgcn_s_setprio(0);
    }
  }

  __syncthreads();
  if (ksp == 1) {
    if (h == 0) { mlbuf[qsub * 64 + ql] = m_run; mlbuf[qsub * 64 + 32 + ql] = l_run; }
    float* ob = (float*)(smem + qsub * 16384);
#pragma unroll
    for (int df = 0; df < 4; ++df)
#pragma unroll
      for (int r = 0; r < 16; ++r) {
        int d = df * 32 + (r & 3) + 8 * (r >> 2) + 4 * h;
        ob[d * 32 + ql] = ofr[df][r];
      }
  }
  __syncthreads();
  if (ksp == 0) {
    float m2 = mlbuf[qsub * 64 + ql], l2 = mlbuf[qsub * 64 + 32 + ql];
    float mstar = fmaxf(m_run, m2);
    float f1 = __builtin_amdgcn_exp2f(m_run - mstar);
    float f2 = (l2 > 0.f) ? __builtin_amdgcn_exp2f(m2 - mstar) : 0.f;
    float lstar = l_run * f1 + l2 * f2;
    float inv = 1.0f / lstar;
    float a1 = f1 * inv, a2 = f2 * inv;
    const float* ob = (const float*)(smem + qsub * 16384);
    ushort* orow = Ob + (size_t)(q0 + qsub * 32 + ql) * DIMc + head * 128;
#pragma unroll
    for (int df = 0; df < 4; ++df)
#pragma unroll
      for (int G = 0; G < 4; ++G) {
        int d0 = df * 32 + 8 * G + 4 * h;
        float v0 = ofr[df][G * 4 + 0] * a1 + ob[(d0 + 0) * 32 + ql] * a2;
        float v1 = ofr[df][G * 4 + 1] * a1 + ob[(d0 + 1) * 32 + ql] * a2;
        float v2 = ofr[df][G * 4 + 2] * a1 + ob[(d0 + 2) * 32 + ql] * a2;
        float v3 = ofr[df][G * 4 + 3] * a1 + ob[(d0 + 3) * 32 + ql] * a2;
        uint2 o; o.x = pack2(v0, v1); o.y = pack2(v2, v3);
        *(uint2*)(orow + d0) = o;
      }
  }
}

// ---------------- host ----------------
extern "C" void kernel_launch(void* const* d_in, const int* in_sizes, int n_in,
                              void* d_out, int out_size, void* d_ws, size_t ws_size,
                              hipStream_t stream) {
  const float* x  = (const float*)d_in[0];
  const float* fc = (const float*)d_in[1];
  const float* fs = (const float*)d_in[2];
  const float* Wq = (const float*)d_in[3];
  const float* bq = (const float*)d_in[4];
  const float* Wk = (const float*)d_in[5];
  const float* bk = (const float*)d_in[6];
  const float* Wv = (const float*)d_in[7];
  const float* bv = (const float*)d_in[8];
  const float* Wo = (const float*)d_in[9];
  const float* bo = (const float*)d_in[10];
  const float* gq = (const float*)d_in[11];
  const float* gk = (const float*)d_in[12];
  const int* seq  = (const int*)d_in[13];
  const int* pH   = (const int*)d_in[15];
  const int* pW   = (const int*)d_in[16];

  const int DIMc = in_sizes[4];          // 2048
  const int S_   = in_sizes[0] / DIMc;   // 2048

  char* ws = (char*)d_ws;
  const size_t MB = 1024ull * 1024ull;
  ushort* xb    = (ushort*)(ws + 0 * MB);
  ushort* Wqkvb = (ushort*)(ws + 8 * MB);    // [6144][2048] bf16 = 24 MB
  ushort* Wob   = (ushort*)(ws + 32 * MB);
  float*  qpre  = (float*)(ws + 40 * MB);    // 16 MB
  float*  kpre  = (float*)(ws + 56 * MB);    // 16 MB
  ushort* Qb    = (ushort*)(ws + 72 * MB);
  ushort* Kb    = (ushort*)(ws + 80 * MB);
  ushort* Vt    = (ushort*)(ws + 88 * MB);
  ushort* Ob    = (ushort*)(ws + 40 * MB);   // aliases qpre (dead after fuse)
  float*  pbuf  = (float*)(ws + 56 * MB);    // 32 MB, aliases kpre/Qb/Kb (dead by then)

  const int nx8 = (S_ * DIMc) / 8;
  const int nw8 = (DIMc * DIMc) / 8;
  cvt_x<<<(nx8 + 255) / 256, 256, 0, stream>>>(x, xb, nx8);
  cvt_w4<<<dim3((nw8 + 255) / 256, 4), 256, 0, stream>>>(Wq, Wk, Wv, Wo, Wqkvb, Wob, nw8);

  gemm_qkv256<<<dim3(3 * DIMc / 256, S_ / 256), 512, 0, stream>>>(
      xb, Wqkvb, bq, bk, bv, qpre, kpre, Vt, DIMc, S_);

  const float foldq = LOG2E / sqrtf((float)(DIMc / 16));
  fuse_rms_rope<<<dim3(S_, 2), 256, 0, stream>>>(qpre, kpre, gq, gk, fc, fs, pH, pW,
                                                 Qb, Kb, DIMc, foldq);

  attn32<<<dim3(S_ / 128, 16), 512, 0, stream>>>(Qb, Kb, Vt, Ob, seq, S_, DIMc);

  gemm_wo<<<dim3(16, 16, 2), 512, 0, stream>>>(Ob, Wob, pbuf, DIMc);
  reduce_wo<<<(S_ * DIMc / 4 + 255) / 256, 256, 0, stream>>>(pbuf, bo, (float*)d_out,
                                                             S_ * DIMc / 4);
}

// Round 7
// 190.877 us; speedup vs baseline: 1.0101x; 1.0101x over previous
//
#include <hip/hip_runtime.h>
#include <cstdint>
#include <cmath>

typedef unsigned int uint;
typedef unsigned short ushort;
typedef __bf16 bf16_t;
typedef bf16_t bf16x8 __attribute__((ext_vector_type(8)));
typedef float f32x4 __attribute__((ext_vector_type(4)));
typedef float f32x16 __attribute__((ext_vector_type(16)));

#define LOG2E 1.44269504088896340736f

__device__ __forceinline__ ushort f2bf(float f) {
  uint x = __float_as_uint(f);
  x += 0x7fffu + ((x >> 16) & 1u);   // RNE to bf16
  return (ushort)(x >> 16);
}
__device__ __forceinline__ uint pack2(float lo, float hi) {
  return (uint)f2bf(lo) | ((uint)f2bf(hi) << 16);
}
__device__ __forceinline__ uint cvt_pk_bf16(float lo, float hi) {
  uint r;
  asm("v_cvt_pk_bf16_f32 %0, %1, %2" : "=v"(r) : "v"(lo), "v"(hi));
  return r;
}

// global -> LDS direct copy, 16B per lane; LDS dest is wave-uniform base + lane*16.
__device__ __forceinline__ void gload_lds16(const void* gsrc, void* ldsdst) {
  typedef const __attribute__((address_space(1))) unsigned int* gp_t;
  typedef __attribute__((address_space(3))) unsigned int* lp_t;
  __builtin_amdgcn_global_load_lds((gp_t)(uintptr_t)gsrc,
                                   (lp_t)(unsigned int)(uintptr_t)ldsdst,
                                   16, 0, 0);
}

// ---------------- fp32 -> bf16 converts: x + 4 weights in ONE launch ----------------
// y=0 -> x (nx8 items), y=1..3 -> Wq/Wk/Wv into Wqkvb, y=4 -> Wo into Wob (nw8 items).
__global__ __launch_bounds__(256) void cvt5(const float* __restrict__ x,
                                            const float* __restrict__ wq,
                                            const float* __restrict__ wk,
                                            const float* __restrict__ wv,
                                            const float* __restrict__ wo,
                                            ushort* __restrict__ xb,
                                            ushort* __restrict__ wqkv,
                                            ushort* __restrict__ wob,
                                            int nx8, int nw8) {
  const int y = blockIdx.y;
  const float* src;
  ushort* dst;
  int n8;
  if (y == 0)      { src = x;  dst = xb;  n8 = nx8; }
  else if (y == 4) { src = wo; dst = wob; n8 = nw8; }
  else {
    src = (y == 1) ? wq : (y == 2) ? wk : wv;
    dst = wqkv + (size_t)(y - 1) * nw8 * 8;
    n8 = nw8;
  }
  int i = blockIdx.x * blockDim.x + threadIdx.x;
  if (i >= n8) return;
  const float4* s4 = (const float4*)src;
  float4 a = s4[i * 2], b = s4[i * 2 + 1];
  uint4 o;
  o.x = pack2(a.x, a.y); o.y = pack2(a.z, a.w);
  o.z = pack2(b.x, b.y); o.w = pack2(b.z, b.w);
  ((uint4*)dst)[i] = o;
}

// ---------------- fused QKV GEMM: 256x256 tile, BK=64, 8 waves, counted-vmcnt pipeline
// Wave grid 2(M)x4(N); per-wave C = 128x64 (acc[8][4] of 16x16 frags).
// LDS: 2 K-tile buffers x (A 256x64 + B 256x64) bf16 = 128 KiB.
// Swizzle: LDS[row][chunk] = G[row][chunk ^ (row&7)] (both-sides, conflict-free b128;
// verified R6: SQ_LDS_BANK_CONFLICT == 0).
// T4: all 8 stage loads for tile j+1 issued at HEAD of iter j (into the buffer whose
// last reads completed before iter j-1's end barrier), then vmcnt(8) = wait tile-j's
// loads only; j+1's loads stay in flight across the whole iteration. No drain in loop.
__global__ __launch_bounds__(512, 2) void gemm_qkv256(const ushort* __restrict__ A,
                                                      const ushort* __restrict__ B,
                                                      const float* __restrict__ bq,
                                                      const float* __restrict__ bk,
                                                      const float* __restrict__ bv,
                                                      float* __restrict__ qpre,
                                                      float* __restrict__ kpre,
                                                      ushort* __restrict__ Vt,
                                                      int K, int S_) {
  __shared__ __align__(16) unsigned char lds[131072];   // A: [2][32768]; B at +65536
  const int t = threadIdx.x, l = t & 63;
  const int w = t >> 6;
  const int g = l >> 4, c = l & 15;
  const int wr = w >> 2, wc = w & 3;          // 2 x 4 wave grid
  const int tm = blockIdx.y * 256, tn = blockIdx.x * 256;

  const int srow = t >> 3;                    // 0..63
  const int schunk = (t & 7) ^ (srow & 7);    // pre-swizzled source chunk
  const ushort* Ag = A + (size_t)(tm + srow) * K + schunk * 8;
  const ushort* Bg = B + (size_t)(tn + srow) * K + schunk * 8;
  const size_t rK64 = (size_t)64 * K;

#define STAGE_A(nb, kt) do { const ushort* s_ = Ag + (size_t)(kt) * 64;          \
    gload_lds16(s_,            lds + (nb) * 32768 + t * 16);                     \
    gload_lds16(s_ + rK64,     lds + (nb) * 32768 + 8192 + t * 16);              \
    gload_lds16(s_ + 2 * rK64, lds + (nb) * 32768 + 16384 + t * 16);             \
    gload_lds16(s_ + 3 * rK64, lds + (nb) * 32768 + 24576 + t * 16); } while (0)
#define STAGE_B(nb, kt) do { const ushort* s_ = Bg + (size_t)(kt) * 64;          \
    gload_lds16(s_,            lds + 65536 + (nb) * 32768 + t * 16);             \
    gload_lds16(s_ + rK64,     lds + 65536 + (nb) * 32768 + 8192 + t * 16);      \
    gload_lds16(s_ + 2 * rK64, lds + 65536 + (nb) * 32768 + 16384 + t * 16);     \
    gload_lds16(s_ + 3 * rK64, lds + 65536 + (nb) * 32768 + 24576 + t * 16); } while (0)

  f32x4 acc[8][4] = {};
  bf16x8 af[2][4], bf[2][4];

#define RD_A(QM) do {                                                            \
    _Pragma("unroll") for (int ks = 0; ks < 2; ++ks)                             \
    _Pragma("unroll") for (int mm = 0; mm < 4; ++mm) {                           \
      int rh = (QM) * 64 + mm * 16 + c;                                          \
      af[ks][mm] = *(const bf16x8*)(Ab + rh * 128 + (((ks * 4 + g) ^ (rh & 7)) << 4)); } \
  } while (0)
#define RD_B() do {                                                              \
    _Pragma("unroll") for (int ks = 0; ks < 2; ++ks)                             \
    _Pragma("unroll") for (int nn = 0; nn < 4; ++nn) {                           \
      int rh = (wc & 1) * 64 + nn * 16 + c;                                      \
      bf[ks][nn] = *(const bf16x8*)(Bb + rh * 128 + (((ks * 4 + g) ^ (rh & 7)) << 4)); } \
  } while (0)
#define MFMA_Q(QM, QN) do {                                                      \
    __builtin_amdgcn_s_setprio(1);                                               \
    _Pragma("unroll") for (int mm = 0; mm < 4; ++mm)                             \
    _Pragma("unroll") for (int nn = 0; nn < 2; ++nn) {                           \
      acc[(QM)*4+mm][(QN)*2+nn] = __builtin_amdgcn_mfma_f32_16x16x32_bf16(       \
          af[0][mm], bf[0][(QN)*2+nn], acc[(QM)*4+mm][(QN)*2+nn], 0, 0, 0);      \
      acc[(QM)*4+mm][(QN)*2+nn] = __builtin_amdgcn_mfma_f32_16x16x32_bf16(       \
          af[1][mm], bf[1][(QN)*2+nn], acc[(QM)*4+mm][(QN)*2+nn], 0, 0, 0); }    \
    __builtin_amdgcn_s_setprio(0);                                               \
  } while (0)

  const int NT = K >> 6;   // 32 K-tiles
  // prologue: stage tile 0 into buf 0
  STAGE_A(0, 0);
  STAGE_B(0, 0);

  for (int j = 0; j < NT; ++j) {
    const int buf = j & 1, nb = buf ^ 1;
    const unsigned char* Ab = lds + buf * 32768 + wr * 16384;
    const unsigned char* Bb = lds + 65536 + buf * 32768 + (wc >> 1) * 16384;
    const bool st = (j + 1) < NT;
    if (st) {
      // tile j+1 -> buffer nb; nb's last readers finished before iter j-1's end barrier
      STAGE_A(nb, j + 1);
      STAGE_B(nb, j + 1);
      asm volatile("s_waitcnt vmcnt(8)" ::: "memory");   // tile j landed; j+1 in flight
    } else {
      asm volatile("s_waitcnt vmcnt(0)" ::: "memory");
    }
    __builtin_amdgcn_s_barrier();    // cross-wave visibility of tile j's staging

    RD_A(0); RD_B();
    MFMA_Q(0, 0);
    MFMA_Q(0, 1);
    RD_A(1);
    MFMA_Q(1, 0);
    MFMA_Q(1, 1);

    __builtin_amdgcn_s_barrier();    // all reads of buf done -> next iter may overwrite
  }

#undef STAGE_A
#undef STAGE_B
#undef RD_A
#undef RD_B
#undef MFMA_Q

  const int sel = tn >> 11;   // uniform per block (2048 % 256 == 0)
  if (sel < 2) {
    float* outp = sel ? kpre : qpre;
    const float* bias = sel ? bk : bq;
#pragma unroll
    for (int n = 0; n < 4; ++n) {
      int col = (tn & 2047) + wc * 64 + n * 16 + c;
      float bvv = bias[col];
#pragma unroll
      for (int m = 0; m < 8; ++m) {
        int row0 = tm + wr * 128 + m * 16 + g * 4;
#pragma unroll
        for (int i = 0; i < 4; ++i)
          outp[(size_t)(row0 + i) * 2048 + col] = acc[m][n][i] + bvv;
      }
    }
  } else {
#pragma unroll
    for (int n = 0; n < 4; ++n) {
      int colv = (tn - 4096) + wc * 64 + n * 16 + c;
      float bvv = bv[colv];
#pragma unroll
      for (int m = 0; m < 8; ++m) {
        int row0 = tm + wr * 128 + m * 16 + g * 4;
        uint2 o;
        o.x = pack2(acc[m][n][0] + bvv, acc[m][n][1] + bvv);
        o.y = pack2(acc[m][n][2] + bvv, acc[m][n][3] + bvv);
        *(uint2*)(Vt + (size_t)colv * S_ + row0) = o;
      }
    }
  }
}

// ---------------- Wo GEMM split-K=2, 8 waves (proven R5) -> fp32 partials ------
__global__ __launch_bounds__(512) void gemm_wo(const ushort* __restrict__ A,
                                               const ushort* __restrict__ B,
                                               float* __restrict__ pbuf, int K) {
  __shared__ __align__(16) unsigned char As[8192];
  __shared__ __align__(16) unsigned char Bs[8192];
  const int t = threadIdx.x, l = t & 63, w = t >> 6;
  const int g = l >> 4, c = l & 15;
  const int wr = w >> 1, wc = w & 1;
  const int tm = blockIdx.y * 128, tn = blockIdx.x * 128;
  const int ks = blockIdx.z;
  const int k0 = ks * (K >> 1), k1 = k0 + (K >> 1);

  const int srow = w * 16 + (l >> 2);
  const int schunk = (l & 3) ^ (srow & 3);
  const ushort* Ag = A + (size_t)(tm + srow) * K + schunk * 8;
  const ushort* Bg = B + (size_t)(tn + srow) * K + schunk * 8;
  void* AsBase = (void*)(As + w * 1024);
  void* BsBase = (void*)(Bs + w * 1024);

  f32x4 acc[2][4] = {};

  for (int kt = k0; kt < k1; kt += 32) {
    __syncthreads();
    gload_lds16(Ag + kt, AsBase);
    gload_lds16(Bg + kt, BsBase);
    __syncthreads();
    bf16x8 af[2], bfr[4];
#pragma unroll
    for (int m = 0; m < 2; ++m) {
      int row = wr * 32 + m * 16 + c;
      af[m] = *(const bf16x8*)(As + row * 64 + ((g ^ (row & 3)) << 4));
    }
#pragma unroll
    for (int n = 0; n < 4; ++n) {
      int row = wc * 64 + n * 16 + c;
      bfr[n] = *(const bf16x8*)(Bs + row * 64 + ((g ^ (row & 3)) << 4));
    }
#pragma unroll
    for (int m = 0; m < 2; ++m)
#pragma unroll
      for (int n = 0; n < 4; ++n)
        acc[m][n] = __builtin_amdgcn_mfma_f32_16x16x32_bf16(af[m], bfr[n], acc[m][n], 0, 0, 0);
  }

  float* out = pbuf + (size_t)ks * 2048 * 2048;
#pragma unroll
  for (int n = 0; n < 4; ++n) {
    int col = tn + wc * 64 + n * 16 + c;
#pragma unroll
    for (int m = 0; m < 2; ++m) {
      int row0 = tm + wr * 32 + m * 16 + g * 4;
#pragma unroll
      for (int i = 0; i < 4; ++i)
        out[(size_t)(row0 + i) * 2048 + col] = acc[m][n][i];
    }
  }
}

__global__ __launch_bounds__(256) void reduce_wo(const float* __restrict__ p,
                                                 const float* __restrict__ bo,
                                                 float* __restrict__ out, int n4) {
  int i = blockIdx.x * blockDim.x + threadIdx.x;
  if (i >= n4) return;
  float4 a = ((const float4*)p)[i];
  float4 b = ((const float4*)p)[i + n4];
  float4 bb = *(const float4*)(bo + ((i * 4) & 2047));
  float4 o;
  o.x = a.x + b.x + bb.x; o.y = a.y + b.y + bb.y;
  o.z = a.z + b.z + bb.z; o.w = a.w + b.w + bb.w;
  ((float4*)out)[i] = o;
}

// ---------------- fused rmsnorm + 3-axis RoPE + scale-fold, fp32 -> bf16 ----------------
__global__ __launch_bounds__(256) void fuse_rms_rope(const float* __restrict__ qpre,
                                                     const float* __restrict__ kpre,
                                                     const float* __restrict__ gq,
                                                     const float* __restrict__ gk,
                                                     const float* __restrict__ fc,
                                                     const float* __restrict__ fs,
                                                     const int* __restrict__ pH,
                                                     const int* __restrict__ pW,
                                                     ushort* __restrict__ Qb,
                                                     ushort* __restrict__ Kb,
                                                     int dim, float foldq) {
  const int which = blockIdx.y;
  const float* pre = which ? kpre : qpre;
  const float* gw = which ? gk : gq;
  ushort* outp = which ? Kb : Qb;
  const float fold = which ? 1.0f : foldq;

  const int p = blockIdx.x, t = threadIdx.x;
  const float* row = pre + (size_t)p * dim;
  float v[8];
  {
    float4 a = *(const float4*)(row + t * 8);
    float4 b = *(const float4*)(row + t * 8 + 4);
    v[0] = a.x; v[1] = a.y; v[2] = a.z; v[3] = a.w;
    v[4] = b.x; v[5] = b.y; v[6] = b.z; v[7] = b.w;
  }
  float ss = 0.f;
#pragma unroll
  for (int i = 0; i < 8; ++i) ss += v[i] * v[i];
#pragma unroll
  for (int off = 32; off; off >>= 1) ss += __shfl_xor(ss, off);
  __shared__ float wsum[4];
  if ((t & 63) == 0) wsum[t >> 6] = ss;
  __syncthreads();
  float rstd = rsqrtf((wsum[0] + wsum[1] + wsum[2] + wsum[3]) * (1.0f / dim) + 1e-6f);
  float gv[8];
  {
    float4 a = *(const float4*)(gw + t * 8);
    float4 b = *(const float4*)(gw + t * 8 + 4);
    gv[0] = a.x; gv[1] = a.y; gv[2] = a.z; gv[3] = a.w;
    gv[4] = b.x; gv[5] = b.y; gv[6] = b.z; gv[7] = b.w;
  }
#pragma unroll
  for (int i = 0; i < 8; ++i) v[i] = v[i] * rstd * gv[i];

  const int H = pH[0], W = pW[0];
  const int hw = H * W;
  const int fr = p / hw;
  const int rem = p - fr * hw;
  const int hh = rem / W;
  const int ww = rem - hh * W;
  const int hd = dim / 16;
  const int cd = hd >> 1;
  const int c2 = cd / 3, c1 = cd - 2 * c2;
  const int j0 = ((t * 8) % hd) >> 1;

  uint ob[4];
#pragma unroll
  for (int q = 0; q < 4; ++q) {
    int j = j0 + q;
    int ri = (j < c1) ? fr : ((j < c1 + c2) ? hh : ww);
    float cs = fc[ri * cd + j];
    float sn = fs[ri * cd + j];
    float a = v[2 * q], b = v[2 * q + 1];
    ob[q] = pack2((a * cs - b * sn) * fold, (a * sn + b * cs) * fold);
  }
  uint4 o4; o4.x = ob[0]; o4.y = ob[1]; o4.z = ob[2]; o4.w = ob[3];
  *(uint4*)(outp + (size_t)p * dim + t * 8) = o4;
}

// ---------------- flash attention, 32x32 MFMA, 4 q-subtiles x 2 KV-splits ----------------
__global__ __launch_bounds__(512, 2) void attn32(const ushort* __restrict__ Qb,
                                                 const ushort* __restrict__ Kb,
                                                 const ushort* __restrict__ Vt,
                                                 ushort* __restrict__ Ob,
                                                 const int* __restrict__ seq_lens,
                                                 int S_, int DIMc) {
  __shared__ __align__(16) unsigned char smem[66560];
  float* mlbuf = (float*)(smem + 65536);
  const int t = threadIdx.x, l = t & 63, w = t >> 6;
  const int qsub = w & 3, ksp = w >> 2;
  const int h = l >> 5, ql = l & 31;

  const int orig = blockIdx.y * gridDim.x + blockIdx.x;
  const int nwg = gridDim.x * gridDim.y;
  const int lin = (orig & 7) * (nwg >> 3) + (orig >> 3);
  const int q0 = (lin % gridDim.x) * 128;
  const int head = lin / gridDim.x;
  const int kvlen = seq_lens[0];

  unsigned char* sk_s = smem + ksp * 16384;
  unsigned char* sv_s = smem + 32768 + ksp * 16384;

  bf16x8 qf[8];
  {
    const ushort* qp = Qb + (size_t)(q0 + qsub * 32 + ql) * DIMc + head * 128 + h * 8;
#pragma unroll
    for (int s = 0; s < 8; ++s) qf[s] = *(const bf16x8*)(qp + s * 16);
  }

  f32x16 ofr[4] = {};
  float m_run = -1e30f, l_run = 0.f;

  const int nt = (kvlen + 63) >> 6;
  const int half = (nt + 1) >> 1;
  const int tbase = ksp ? half : 0;
  const int mycnt = ksp ? (nt - half) : half;

  for (int tt = 0; tt < half; ++tt) {
    __syncthreads();
    if (tt < mycnt) {
      const int kv0 = (tbase + tt) * 64;
#pragma unroll
      for (int it = 0; it < 4; ++it) {
        int kr = qsub * 16 + it * 4 + (l >> 4);
        int kc = (l & 15) ^ (kr & 15);
        gload_lds16(Kb + (size_t)(kv0 + kr) * DIMc + head * 128 + kc * 8,
                    sk_s + qsub * 4096 + it * 1024);
        int vr = qsub * 32 + it * 8 + (l >> 3);
        int vc = (l & 7) ^ (vr & 7);
        gload_lds16(Vt + (size_t)(head * 128 + vr) * S_ + kv0 + vc * 8,
                    sv_s + qsub * 4096 + it * 1024);
      }
    }
    __syncthreads();
    if (tt >= mycnt) continue;
    const int kv0 = (tbase + tt) * 64;

    f32x16 sfr[2] = {};
    __builtin_amdgcn_s_setprio(1);
#pragma unroll
    for (int kb = 0; kb < 2; ++kb) {
      const unsigned char* kbp = sk_s + (kb * 32 + ql) * 256;
      const int rx = (kb * 32 + ql) & 15;
#pragma unroll
      for (int s = 0; s < 8; ++s) {
        bf16x8 kf = *(const bf16x8*)(kbp + (((s * 2 + h) ^ rx) << 4));
        sfr[kb] = __builtin_amdgcn_mfma_f32_32x32x16_bf16(kf, qf[s], sfr[kb], 0, 0, 0);
      }
    }
    __builtin_amdgcn_s_setprio(0);

    if (kv0 + 64 > kvlen) {
#pragma unroll
      for (int kb = 0; kb < 2; ++kb)
#pragma unroll
        for (int r = 0; r < 16; ++r) {
          int key = kv0 + kb * 32 + (r & 3) + 8 * (r >> 2) + 4 * h;
          if (key >= kvlen) sfr[kb][r] = -1e30f;
        }
    }

    float mt = -1e30f;
#pragma unroll
    for (int kb = 0; kb < 2; ++kb)
#pragma unroll
      for (int r = 0; r < 16; ++r) mt = fmaxf(mt, sfr[kb][r]);
    mt = fmaxf(mt, __shfl_xor(mt, 32));

    if (!__all(mt <= m_run + 8.0f)) {
      float m_new = fmaxf(m_run, mt);
      float fac = __builtin_amdgcn_exp2f(m_run - m_new);
      l_run *= fac;
#pragma unroll
      for (int df = 0; df < 4; ++df) ofr[df] *= fac;
      m_run = m_new;
    }

    float ls = 0.f;
    uint u[2][4][2];
#pragma unroll
    for (int kb = 0; kb < 2; ++kb)
#pragma unroll
      for (int G = 0; G < 4; ++G) {
        float p0 = __builtin_amdgcn_exp2f(sfr[kb][G * 4 + 0] - m_run);
        float p1 = __builtin_amdgcn_exp2f(sfr[kb][G * 4 + 1] - m_run);
        float p2 = __builtin_amdgcn_exp2f(sfr[kb][G * 4 + 2] - m_run);
        float p3 = __builtin_amdgcn_exp2f(sfr[kb][G * 4 + 3] - m_run);
        ls += (p0 + p1) + (p2 + p3);
        u[kb][G][0] = cvt_pk_bf16(p0, p1);
        u[kb][G][1] = cvt_pk_bf16(p2, p3);
      }
    ls += __shfl_xor(ls, 32);
    l_run += ls;

#pragma unroll
    for (int ks = 0; ks < 4; ++ks) {
      const int kb = ks >> 1, G0 = (ks & 1) * 2;
      uint own0 = h ? u[kb][G0 + 1][0] : u[kb][G0][0];
      uint own1 = h ? u[kb][G0 + 1][1] : u[kb][G0][1];
      uint snd0 = h ? u[kb][G0][0] : u[kb][G0 + 1][0];
      uint snd1 = h ? u[kb][G0][1] : u[kb][G0 + 1][1];
      uint rcv0 = __shfl_xor(snd0, 32);
      uint rcv1 = __shfl_xor(snd1, 32);
      union { uint4 q; bf16x8 b; } uu;
      uu.q.x = h ? rcv0 : own0;
      uu.q.y = h ? rcv1 : own1;
      uu.q.z = h ? own0 : rcv0;
      uu.q.w = h ? own1 : rcv1;
      __builtin_amdgcn_s_setprio(1);
#pragma unroll
      for (int df = 0; df < 4; ++df) {
        const int row = df * 32 + ql;
        bf16x8 vf = *(const bf16x8*)(sv_s + row * 128 + (((ks * 2 + h) ^ (row & 7)) << 4));
        ofr[df] = __builtin_amdgcn_mfma_f32_32x32x16_bf16(vf, uu.b, ofr[df], 0, 0, 0);
      }
      __builtin_amdgcn_s_setprio(0);
    }
  }

  __syncthreads();
  if (ksp == 1) {
    if (h == 0) { mlbuf[qsub * 64 + ql] = m_run; mlbuf[qsub * 64 + 32 + ql] = l_run; }
    float* ob = (float*)(smem + qsub * 16384);
#pragma unroll
    for (int df = 0; df < 4; ++df)
#pragma unroll
      for (int r = 0; r < 16; ++r) {
        int d = df * 32 + (r & 3) + 8 * (r >> 2) + 4 * h;
        ob[d * 32 + ql] = ofr[df][r];
      }
  }
  __syncthreads();
  if (ksp == 0) {
    float m2 = mlbuf[qsub * 64 + ql], l2 = mlbuf[qsub * 64 + 32 + ql];
    float mstar = fmaxf(m_run, m2);
    float f1 = __builtin_amdgcn_exp2f(m_run - mstar);
    float f2 = (l2 > 0.f) ? __builtin_amdgcn_exp2f(m2 - mstar) : 0.f;
    float lstar = l_run * f1 + l2 * f2;
    float inv = 1.0f / lstar;
    float a1 = f1 * inv, a2 = f2 * inv;
    const float* ob = (const float*)(smem + qsub * 16384);
    ushort* orow = Ob + (size_t)(q0 + qsub * 32 + ql) * DIMc + head * 128;
#pragma unroll
    for (int df = 0; df < 4; ++df)
#pragma unroll
      for (int G = 0; G < 4; ++G) {
        int d0 = df * 32 + 8 * G + 4 * h;
        float v0 = ofr[df][G * 4 + 0] * a1 + ob[(d0 + 0) * 32 + ql] * a2;
        float v1 = ofr[df][G * 4 + 1] * a1 + ob[(d0 + 1) * 32 + ql] * a2;
        float v2 = ofr[df][G * 4 + 2] * a1 + ob[(d0 + 2) * 32 + ql] * a2;
        float v3 = ofr[df][G * 4 + 3] * a1 + ob[(d0 + 3) * 32 + ql] * a2;
        uint2 o; o.x = pack2(v0, v1); o.y = pack2(v2, v3);
        *(uint2*)(orow + d0) = o;
      }
  }
}

// ---------------- host ----------------
extern "C" void kernel_launch(void* const* d_in, const int* in_sizes, int n_in,
                              void* d_out, int out_size, void* d_ws, size_t ws_size,
                              hipStream_t stream) {
  const float* x  = (const float*)d_in[0];
  const float* fc = (const float*)d_in[1];
  const float* fs = (const float*)d_in[2];
  const float* Wq = (const float*)d_in[3];
  const float* bq = (const float*)d_in[4];
  const float* Wk = (const float*)d_in[5];
  const float* bk = (const float*)d_in[6];
  const float* Wv = (const float*)d_in[7];
  const float* bv = (const float*)d_in[8];
  const float* Wo = (const float*)d_in[9];
  const float* bo = (const float*)d_in[10];
  const float* gq = (const float*)d_in[11];
  const float* gk = (const float*)d_in[12];
  const int* seq  = (const int*)d_in[13];
  const int* pH   = (const int*)d_in[15];
  const int* pW   = (const int*)d_in[16];

  const int DIMc = in_sizes[4];          // 2048
  const int S_   = in_sizes[0] / DIMc;   // 2048

  char* ws = (char*)d_ws;
  const size_t MB = 1024ull * 1024ull;
  ushort* xb    = (ushort*)(ws + 0 * MB);
  ushort* Wqkvb = (ushort*)(ws + 8 * MB);    // [6144][2048] bf16 = 24 MB
  ushort* Wob   = (ushort*)(ws + 32 * MB);
  float*  qpre  = (float*)(ws + 40 * MB);    // 16 MB
  float*  kpre  = (float*)(ws + 56 * MB);    // 16 MB
  ushort* Qb    = (ushort*)(ws + 72 * MB);
  ushort* Kb    = (ushort*)(ws + 80 * MB);
  ushort* Vt    = (ushort*)(ws + 88 * MB);
  ushort* Ob    = (ushort*)(ws + 40 * MB);   // aliases qpre (dead after fuse)
  float*  pbuf  = (float*)(ws + 56 * MB);    // 32 MB, aliases kpre/Qb/Kb (dead by then)

  const int nx8 = (S_ * DIMc) / 8;
  const int nw8 = (DIMc * DIMc) / 8;
  const int nmax = (nx8 > nw8 ? nx8 : nw8);
  cvt5<<<dim3((nmax + 255) / 256, 5), 256, 0, stream>>>(x, Wq, Wk, Wv, Wo,
                                                        xb, Wqkvb, Wob, nx8, nw8);

  gemm_qkv256<<<dim3(3 * DIMc / 256, S_ / 256), 512, 0, stream>>>(
      xb, Wqkvb, bq, bk, bv, qpre, kpre, Vt, DIMc, S_);

  const float foldq = LOG2E / sqrtf((float)(DIMc / 16));
  fuse_rms_rope<<<dim3(S_, 2), 256, 0, stream>>>(qpre, kpre, gq, gk, fc, fs, pH, pW,
                                                 Qb, Kb, DIMc, foldq);

  attn32<<<dim3(S_ / 128, 16), 512, 0, stream>>>(Qb, Kb, Vt, Ob, seq, S_, DIMc);

  gemm_wo<<<dim3(16, 16, 2), 512, 0, stream>>>(Ob, Wob, pbuf, DIMc);
  reduce_wo<<<(S_ * DIMc / 4 + 255) / 256, 256, 0, stream>>>(pbuf, bo, (float*)d_out,
                                                             S_ * DIMc / 4);
}

// Round 8
// 187.429 us; speedup vs baseline: 1.0287x; 1.0184x over previous
//
#include <hip/hip_runtime.h>
#include <cstdint>
#include <cmath>

typedef unsigned int uint;
typedef unsigned short ushort;
typedef __bf16 bf16_t;
typedef bf16_t bf16x8 __attribute__((ext_vector_type(8)));
typedef float f32x4 __attribute__((ext_vector_type(4)));
typedef float f32x16 __attribute__((ext_vector_type(16)));

#define LOG2E 1.44269504088896340736f

__device__ __forceinline__ ushort f2bf(float f) {
  uint x = __float_as_uint(f);
  x += 0x7fffu + ((x >> 16) & 1u);   // RNE to bf16
  return (ushort)(x >> 16);
}
__device__ __forceinline__ uint pack2(float lo, float hi) {
  return (uint)f2bf(lo) | ((uint)f2bf(hi) << 16);
}
__device__ __forceinline__ uint cvt_pk_bf16(float lo, float hi) {
  uint r;
  asm("v_cvt_pk_bf16_f32 %0, %1, %2" : "=v"(r) : "v"(lo), "v"(hi));
  return r;
}

// global -> LDS direct copy, 16B per lane; LDS dest is wave-uniform base + lane*16.
__device__ __forceinline__ void gload_lds16(const void* gsrc, void* ldsdst) {
  typedef const __attribute__((address_space(1))) unsigned int* gp_t;
  typedef __attribute__((address_space(3))) unsigned int* lp_t;
  __builtin_amdgcn_global_load_lds((gp_t)(uintptr_t)gsrc,
                                   (lp_t)(unsigned int)(uintptr_t)ldsdst,
                                   16, 0, 0);
}

// ---------------- fp32 -> bf16 converts: x + 4 weights in ONE launch ----------------
__global__ __launch_bounds__(256) void cvt5(const float* __restrict__ x,
                                            const float* __restrict__ wq,
                                            const float* __restrict__ wk,
                                            const float* __restrict__ wv,
                                            const float* __restrict__ wo,
                                            ushort* __restrict__ xb,
                                            ushort* __restrict__ wqkv,
                                            ushort* __restrict__ wob,
                                            int nx8, int nw8) {
  const int y = blockIdx.y;
  const float* src;
  ushort* dst;
  int n8;
  if (y == 0)      { src = x;  dst = xb;  n8 = nx8; }
  else if (y == 4) { src = wo; dst = wob; n8 = nw8; }
  else {
    src = (y == 1) ? wq : (y == 2) ? wk : wv;
    dst = wqkv + (size_t)(y - 1) * nw8 * 8;
    n8 = nw8;
  }
  int i = blockIdx.x * blockDim.x + threadIdx.x;
  if (i >= n8) return;
  const float4* s4 = (const float4*)src;
  float4 a = s4[i * 2], b = s4[i * 2 + 1];
  uint4 o;
  o.x = pack2(a.x, a.y); o.y = pack2(a.z, a.w);
  o.z = pack2(b.x, b.y); o.w = pack2(b.z, b.w);
  ((uint4*)dst)[i] = o;
}

// ---------------- fused QKV GEMM: R2's proven 128x128/8-wave geometry (768 blocks,
// 0 idle CUs) + LDS double-buffer + counted vmcnt (no per-iter drain).
// Per K-step: stage tile j+1 (2 loads) into buffer nb, vmcnt(2) = tile j landed,
// barrier, 6 ds_read_b128 + 8 MFMA, barrier. Tile j+1's loads fly a full iteration.
// Race-free: nb's last readers passed iter j-1's end barrier before these writes issue.
__global__ __launch_bounds__(512) void gemm_qkv_db(const ushort* __restrict__ A,
                                                   const ushort* __restrict__ B,
                                                   const float* __restrict__ bq,
                                                   const float* __restrict__ bk,
                                                   const float* __restrict__ bv,
                                                   float* __restrict__ qpre,
                                                   float* __restrict__ kpre,
                                                   ushort* __restrict__ Vt,
                                                   int K, int S_) {
  __shared__ __align__(16) unsigned char As[16384];   // 2 buffers x 8 KB
  __shared__ __align__(16) unsigned char Bs[16384];
  const int t = threadIdx.x, l = t & 63, w = t >> 6;
  const int g = l >> 4, c = l & 15;
  const int wr = w >> 1, wc = w & 1;
  const int tm = blockIdx.y * 128, tn = blockIdx.x * 128;

  const int srow = w * 16 + (l >> 2);
  const int schunk = (l & 3) ^ (srow & 3);
  const ushort* Ag = A + (size_t)(tm + srow) * K + schunk * 8;
  const ushort* Bg = B + (size_t)(tn + srow) * K + schunk * 8;

  f32x4 acc[2][4] = {};

  const int NT = K >> 5;   // 64 K-steps of 32
  // prologue: tile 0 -> buffer 0
  gload_lds16(Ag, As + w * 1024);
  gload_lds16(Bg, Bs + w * 1024);

  for (int j = 0; j < NT; ++j) {
    const int buf = j & 1, nb = buf ^ 1;
    if (j + 1 < NT) {
      const int kt1 = (j + 1) << 5;
      gload_lds16(Ag + kt1, As + nb * 8192 + w * 1024);
      gload_lds16(Bg + kt1, Bs + nb * 8192 + w * 1024);
      asm volatile("s_waitcnt vmcnt(2)" ::: "memory");   // tile j landed; j+1 in flight
    } else {
      asm volatile("s_waitcnt vmcnt(0)" ::: "memory");
    }
    __builtin_amdgcn_s_barrier();     // tile j visible to all waves

    const unsigned char* Ab = As + buf * 8192;
    const unsigned char* Bb = Bs + buf * 8192;
    bf16x8 af[2], bfr[4];
#pragma unroll
    for (int m = 0; m < 2; ++m) {
      int row = wr * 32 + m * 16 + c;
      af[m] = *(const bf16x8*)(Ab + row * 64 + ((g ^ (row & 3)) << 4));
    }
#pragma unroll
    for (int n = 0; n < 4; ++n) {
      int row = wc * 64 + n * 16 + c;
      bfr[n] = *(const bf16x8*)(Bb + row * 64 + ((g ^ (row & 3)) << 4));
    }
#pragma unroll
    for (int m = 0; m < 2; ++m)
#pragma unroll
      for (int n = 0; n < 4; ++n)
        acc[m][n] = __builtin_amdgcn_mfma_f32_16x16x32_bf16(af[m], bfr[n], acc[m][n], 0, 0, 0);

    __builtin_amdgcn_s_barrier();     // all reads of buf done -> j+2 may overwrite it
  }

  const int sel = tn >> 11;   // uniform per block
  if (sel < 2) {
    float* outp = sel ? kpre : qpre;
    const float* bias = sel ? bk : bq;
#pragma unroll
    for (int n = 0; n < 4; ++n) {
      int col = (tn & 2047) + wc * 64 + n * 16 + c;
      float bvv = bias[col];
#pragma unroll
      for (int m = 0; m < 2; ++m) {
        int row0 = tm + wr * 32 + m * 16 + g * 4;
#pragma unroll
        for (int i = 0; i < 4; ++i)
          outp[(size_t)(row0 + i) * 2048 + col] = acc[m][n][i] + bvv;
      }
    }
  } else {
#pragma unroll
    for (int n = 0; n < 4; ++n) {
      int colv = (tn - 4096) + wc * 64 + n * 16 + c;
      float bvv = bv[colv];
#pragma unroll
      for (int m = 0; m < 2; ++m) {
        int row0 = tm + wr * 32 + m * 16 + g * 4;
        uint2 o;
        o.x = pack2(acc[m][n][0] + bvv, acc[m][n][1] + bvv);
        o.y = pack2(acc[m][n][2] + bvv, acc[m][n][3] + bvv);
        *(uint2*)(Vt + (size_t)colv * S_ + row0) = o;
      }
    }
  }
}

// ---------------- Wo GEMM split-K=2, same dbuf + counted-vmcnt structure ----------------
__global__ __launch_bounds__(512) void gemm_wo_db(const ushort* __restrict__ A,
                                                  const ushort* __restrict__ B,
                                                  float* __restrict__ pbuf, int K) {
  __shared__ __align__(16) unsigned char As[16384];
  __shared__ __align__(16) unsigned char Bs[16384];
  const int t = threadIdx.x, l = t & 63, w = t >> 6;
  const int g = l >> 4, c = l & 15;
  const int wr = w >> 1, wc = w & 1;
  const int tm = blockIdx.y * 128, tn = blockIdx.x * 128;
  const int ks = blockIdx.z;
  const int k0 = ks * (K >> 1);

  const int srow = w * 16 + (l >> 2);
  const int schunk = (l & 3) ^ (srow & 3);
  const ushort* Ag = A + (size_t)(tm + srow) * K + k0 + schunk * 8;
  const ushort* Bg = B + (size_t)(tn + srow) * K + k0 + schunk * 8;

  f32x4 acc[2][4] = {};

  const int NT = K >> 6;   // (K/2)/32 = 32 K-steps
  gload_lds16(Ag, As + w * 1024);
  gload_lds16(Bg, Bs + w * 1024);

  for (int j = 0; j < NT; ++j) {
    const int buf = j & 1, nb = buf ^ 1;
    if (j + 1 < NT) {
      const int kt1 = (j + 1) << 5;
      gload_lds16(Ag + kt1, As + nb * 8192 + w * 1024);
      gload_lds16(Bg + kt1, Bs + nb * 8192 + w * 1024);
      asm volatile("s_waitcnt vmcnt(2)" ::: "memory");
    } else {
      asm volatile("s_waitcnt vmcnt(0)" ::: "memory");
    }
    __builtin_amdgcn_s_barrier();

    const unsigned char* Ab = As + buf * 8192;
    const unsigned char* Bb = Bs + buf * 8192;
    bf16x8 af[2], bfr[4];
#pragma unroll
    for (int m = 0; m < 2; ++m) {
      int row = wr * 32 + m * 16 + c;
      af[m] = *(const bf16x8*)(Ab + row * 64 + ((g ^ (row & 3)) << 4));
    }
#pragma unroll
    for (int n = 0; n < 4; ++n) {
      int row = wc * 64 + n * 16 + c;
      bfr[n] = *(const bf16x8*)(Bb + row * 64 + ((g ^ (row & 3)) << 4));
    }
#pragma unroll
    for (int m = 0; m < 2; ++m)
#pragma unroll
      for (int n = 0; n < 4; ++n)
        acc[m][n] = __builtin_amdgcn_mfma_f32_16x16x32_bf16(af[m], bfr[n], acc[m][n], 0, 0, 0);

    __builtin_amdgcn_s_barrier();
  }

  float* out = pbuf + (size_t)ks * 2048 * 2048;
#pragma unroll
  for (int n = 0; n < 4; ++n) {
    int col = tn + wc * 64 + n * 16 + c;
#pragma unroll
    for (int m = 0; m < 2; ++m) {
      int row0 = tm + wr * 32 + m * 16 + g * 4;
#pragma unroll
      for (int i = 0; i < 4; ++i)
        out[(size_t)(row0 + i) * 2048 + col] = acc[m][n][i];
    }
  }
}

__global__ __launch_bounds__(256) void reduce_wo(const float* __restrict__ p,
                                                 const float* __restrict__ bo,
                                                 float* __restrict__ out, int n4) {
  int i = blockIdx.x * blockDim.x + threadIdx.x;
  if (i >= n4) return;
  float4 a = ((const float4*)p)[i];
  float4 b = ((const float4*)p)[i + n4];
  float4 bb = *(const float4*)(bo + ((i * 4) & 2047));
  float4 o;
  o.x = a.x + b.x + bb.x; o.y = a.y + b.y + bb.y;
  o.z = a.z + b.z + bb.z; o.w = a.w + b.w + bb.w;
  ((float4*)out)[i] = o;
}

// ---------------- fused rmsnorm + 3-axis RoPE + scale-fold, fp32 -> bf16 ----------------
__global__ __launch_bounds__(256) void fuse_rms_rope(const float* __restrict__ qpre,
                                                     const float* __restrict__ kpre,
                                                     const float* __restrict__ gq,
                                                     const float* __restrict__ gk,
                                                     const float* __restrict__ fc,
                                                     const float* __restrict__ fs,
                                                     const int* __restrict__ pH,
                                                     const int* __restrict__ pW,
                                                     ushort* __restrict__ Qb,
                                                     ushort* __restrict__ Kb,
                                                     int dim, float foldq) {
  const int which = blockIdx.y;
  const float* pre = which ? kpre : qpre;
  const float* gw = which ? gk : gq;
  ushort* outp = which ? Kb : Qb;
  const float fold = which ? 1.0f : foldq;

  const int p = blockIdx.x, t = threadIdx.x;
  const float* row = pre + (size_t)p * dim;
  float v[8];
  {
    float4 a = *(const float4*)(row + t * 8);
    float4 b = *(const float4*)(row + t * 8 + 4);
    v[0] = a.x; v[1] = a.y; v[2] = a.z; v[3] = a.w;
    v[4] = b.x; v[5] = b.y; v[6] = b.z; v[7] = b.w;
  }
  float ss = 0.f;
#pragma unroll
  for (int i = 0; i < 8; ++i) ss += v[i] * v[i];
#pragma unroll
  for (int off = 32; off; off >>= 1) ss += __shfl_xor(ss, off);
  __shared__ float wsum[4];
  if ((t & 63) == 0) wsum[t >> 6] = ss;
  __syncthreads();
  float rstd = rsqrtf((wsum[0] + wsum[1] + wsum[2] + wsum[3]) * (1.0f / dim) + 1e-6f);
  float gv[8];
  {
    float4 a = *(const float4*)(gw + t * 8);
    float4 b = *(const float4*)(gw + t * 8 + 4);
    gv[0] = a.x; gv[1] = a.y; gv[2] = a.z; gv[3] = a.w;
    gv[4] = b.x; gv[5] = b.y; gv[6] = b.z; gv[7] = b.w;
  }
#pragma unroll
  for (int i = 0; i < 8; ++i) v[i] = v[i] * rstd * gv[i];

  const int H = pH[0], W = pW[0];
  const int hw = H * W;
  const int fr = p / hw;
  const int rem = p - fr * hw;
  const int hh = rem / W;
  const int ww = rem - hh * W;
  const int hd = dim / 16;
  const int cd = hd >> 1;
  const int c2 = cd / 3, c1 = cd - 2 * c2;
  const int j0 = ((t * 8) % hd) >> 1;

  uint ob[4];
#pragma unroll
  for (int q = 0; q < 4; ++q) {
    int j = j0 + q;
    int ri = (j < c1) ? fr : ((j < c1 + c2) ? hh : ww);
    float cs = fc[ri * cd + j];
    float sn = fs[ri * cd + j];
    float a = v[2 * q], b = v[2 * q + 1];
    ob[q] = pack2((a * cs - b * sn) * fold, (a * sn + b * cs) * fold);
  }
  uint4 o4; o4.x = ob[0]; o4.y = ob[1]; o4.z = ob[2]; o4.w = ob[3];
  *(uint4*)(outp + (size_t)p * dim + t * 8) = o4;
}

// ---------------- flash attention, 32x32 MFMA, 4 q-subtiles x 2 KV-splits ----------------
__global__ __launch_bounds__(512, 2) void attn32(const ushort* __restrict__ Qb,
                                                 const ushort* __restrict__ Kb,
                                                 const ushort* __restrict__ Vt,
                                                 ushort* __restrict__ Ob,
                                                 const int* __restrict__ seq_lens,
                                                 int S_, int DIMc) {
  __shared__ __align__(16) unsigned char smem[66560];
  float* mlbuf = (float*)(smem + 65536);
  const int t = threadIdx.x, l = t & 63, w = t >> 6;
  const int qsub = w & 3, ksp = w >> 2;
  const int h = l >> 5, ql = l & 31;

  const int orig = blockIdx.y * gridDim.x + blockIdx.x;
  const int nwg = gridDim.x * gridDim.y;
  const int lin = (orig & 7) * (nwg >> 3) + (orig >> 3);
  const int q0 = (lin % gridDim.x) * 128;
  const int head = lin / gridDim.x;
  const int kvlen = seq_lens[0];

  unsigned char* sk_s = smem + ksp * 16384;
  unsigned char* sv_s = smem + 32768 + ksp * 16384;

  bf16x8 qf[8];
  {
    const ushort* qp = Qb + (size_t)(q0 + qsub * 32 + ql) * DIMc + head * 128 + h * 8;
#pragma unroll
    for (int s = 0; s < 8; ++s) qf[s] = *(const bf16x8*)(qp + s * 16);
  }

  f32x16 ofr[4] = {};
  float m_run = -1e30f, l_run = 0.f;

  const int nt = (kvlen + 63) >> 6;
  const int half = (nt + 1) >> 1;
  const int tbase = ksp ? half : 0;
  const int mycnt = ksp ? (nt - half) : half;

  for (int tt = 0; tt < half; ++tt) {
    __syncthreads();
    if (tt < mycnt) {
      const int kv0 = (tbase + tt) * 64;
#pragma unroll
      for (int it = 0; it < 4; ++it) {
        int kr = qsub * 16 + it * 4 + (l >> 4);
        int kc = (l & 15) ^ (kr & 15);
        gload_lds16(Kb + (size_t)(kv0 + kr) * DIMc + head * 128 + kc * 8,
                    sk_s + qsub * 4096 + it * 1024);
        int vr = qsub * 32 + it * 8 + (l >> 3);
        int vc = (l & 7) ^ (vr & 7);
        gload_lds16(Vt + (size_t)(head * 128 + vr) * S_ + kv0 + vc * 8,
                    sv_s + qsub * 4096 + it * 1024);
      }
    }
    __syncthreads();
    if (tt >= mycnt) continue;
    const int kv0 = (tbase + tt) * 64;

    f32x16 sfr[2] = {};
    __builtin_amdgcn_s_setprio(1);
#pragma unroll
    for (int kb = 0; kb < 2; ++kb) {
      const unsigned char* kbp = sk_s + (kb * 32 + ql) * 256;
      const int rx = (kb * 32 + ql) & 15;
#pragma unroll
      for (int s = 0; s < 8; ++s) {
        bf16x8 kf = *(const bf16x8*)(kbp + (((s * 2 + h) ^ rx) << 4));
        sfr[kb] = __builtin_amdgcn_mfma_f32_32x32x16_bf16(kf, qf[s], sfr[kb], 0, 0, 0);
      }
    }
    __builtin_amdgcn_s_setprio(0);

    if (kv0 + 64 > kvlen) {
#pragma unroll
      for (int kb = 0; kb < 2; ++kb)
#pragma unroll
        for (int r = 0; r < 16; ++r) {
          int key = kv0 + kb * 32 + (r & 3) + 8 * (r >> 2) + 4 * h;
          if (key >= kvlen) sfr[kb][r] = -1e30f;
        }
    }

    float mt = -1e30f;
#pragma unroll
    for (int kb = 0; kb < 2; ++kb)
#pragma unroll
      for (int r = 0; r < 16; ++r) mt = fmaxf(mt, sfr[kb][r]);
    mt = fmaxf(mt, __shfl_xor(mt, 32));

    if (!__all(mt <= m_run + 8.0f)) {
      float m_new = fmaxf(m_run, mt);
      float fac = __builtin_amdgcn_exp2f(m_run - m_new);
      l_run *= fac;
#pragma unroll
      for (int df = 0; df < 4; ++df) ofr[df] *= fac;
      m_run = m_new;
    }

    float ls = 0.f;
    uint u[2][4][2];
#pragma unroll
    for (int kb = 0; kb < 2; ++kb)
#pragma unroll
      for (int G = 0; G < 4; ++G) {
        float p0 = __builtin_amdgcn_exp2f(sfr[kb][G * 4 + 0] - m_run);
        float p1 = __builtin_amdgcn_exp2f(sfr[kb][G * 4 + 1] - m_run);
        float p2 = __builtin_amdgcn_exp2f(sfr[kb][G * 4 + 2] - m_run);
        float p3 = __builtin_amdgcn_exp2f(sfr[kb][G * 4 + 3] - m_run);
        ls += (p0 + p1) + (p2 + p3);
        u[kb][G][0] = cvt_pk_bf16(p0, p1);
        u[kb][G][1] = cvt_pk_bf16(p2, p3);
      }
    ls += __shfl_xor(ls, 32);
    l_run += ls;

#pragma unroll
    for (int ks = 0; ks < 4; ++ks) {
      const int kb = ks >> 1, G0 = (ks & 1) * 2;
      uint own0 = h ? u[kb][G0 + 1][0] : u[kb][G0][0];
      uint own1 = h ? u[kb][G0 + 1][1] : u[kb][G0][1];
      uint snd0 = h ? u[kb][G0][0] : u[kb][G0 + 1][0];
      uint snd1 = h ? u[kb][G0][1] : u[kb][G0 + 1][1];
      uint rcv0 = __shfl_xor(snd0, 32);
      uint rcv1 = __shfl_xor(snd1, 32);
      union { uint4 q; bf16x8 b; } uu;
      uu.q.x = h ? rcv0 : own0;
      uu.q.y = h ? rcv1 : own1;
      uu.q.z = h ? own0 : rcv0;
      uu.q.w = h ? own1 : rcv1;
      __builtin_amdgcn_s_setprio(1);
#pragma unroll
      for (int df = 0; df < 4; ++df) {
        const int row = df * 32 + ql;
        bf16x8 vf = *(const bf16x8*)(sv_s + row * 128 + (((ks * 2 + h) ^ (row & 7)) << 4));
        ofr[df] = __builtin_amdgcn_mfma_f32_32x32x16_bf16(vf, uu.b, ofr[df], 0, 0, 0);
      }
      __builtin_amdgcn_s_setprio(0);
    }
  }

  __syncthreads();
  if (ksp == 1) {
    if (h == 0) { mlbuf[qsub * 64 + ql] = m_run; mlbuf[qsub * 64 + 32 + ql] = l_run; }
    float* ob = (float*)(smem + qsub * 16384);
#pragma unroll
    for (int df = 0; df < 4; ++df)
#pragma unroll
      for (int r = 0; r < 16; ++r) {
        int d = df * 32 + (r & 3) + 8 * (r >> 2) + 4 * h;
        ob[d * 32 + ql] = ofr[df][r];
      }
  }
  __syncthreads();
  if (ksp == 0) {
    float m2 = mlbuf[qsub * 64 + ql], l2 = mlbuf[qsub * 64 + 32 + ql];
    float mstar = fmaxf(m_run, m2);
    float f1 = __builtin_amdgcn_exp2f(m_run - mstar);
    float f2 = (l2 > 0.f) ? __builtin_amdgcn_exp2f(m2 - mstar) : 0.f;
    float lstar = l_run * f1 + l2 * f2;
    float inv = 1.0f / lstar;
    float a1 = f1 * inv, a2 = f2 * inv;
    const float* ob = (const float*)(smem + qsub * 16384);
    ushort* orow = Ob + (size_t)(q0 + qsub * 32 + ql) * DIMc + head * 128;
#pragma unroll
    for (int df = 0; df < 4; ++df)
#pragma unroll
      for (int G = 0; G < 4; ++G) {
        int d0 = df * 32 + 8 * G + 4 * h;
        float v0 = ofr[df][G * 4 + 0] * a1 + ob[(d0 + 0) * 32 + ql] * a2;
        float v1 = ofr[df][G * 4 + 1] * a1 + ob[(d0 + 1) * 32 + ql] * a2;
        float v2 = ofr[df][G * 4 + 2] * a1 + ob[(d0 + 2) * 32 + ql] * a2;
        float v3 = ofr[df][G * 4 + 3] * a1 + ob[(d0 + 3) * 32 + ql] * a2;
        uint2 o; o.x = pack2(v0, v1); o.y = pack2(v2, v3);
        *(uint2*)(orow + d0) = o;
      }
  }
}

// ---------------- host ----------------
extern "C" void kernel_launch(void* const* d_in, const int* in_sizes, int n_in,
                              void* d_out, int out_size, void* d_ws, size_t ws_size,
                              hipStream_t stream) {
  const float* x  = (const float*)d_in[0];
  const float* fc = (const float*)d_in[1];
  const float* fs = (const float*)d_in[2];
  const float* Wq = (const float*)d_in[3];
  const float* bq = (const float*)d_in[4];
  const float* Wk = (const float*)d_in[5];
  const float* bk = (const float*)d_in[6];
  const float* Wv = (const float*)d_in[7];
  const float* bv = (const float*)d_in[8];
  const float* Wo = (const float*)d_in[9];
  const float* bo = (const float*)d_in[10];
  const float* gq = (const float*)d_in[11];
  const float* gk = (const float*)d_in[12];
  const int* seq  = (const int*)d_in[13];
  const int* pH   = (const int*)d_in[15];
  const int* pW   = (const int*)d_in[16];

  const int DIMc = in_sizes[4];          // 2048
  const int S_   = in_sizes[0] / DIMc;   // 2048

  char* ws = (char*)d_ws;
  const size_t MB = 1024ull * 1024ull;
  ushort* xb    = (ushort*)(ws + 0 * MB);
  ushort* Wqkvb = (ushort*)(ws + 8 * MB);    // [6144][2048] bf16 = 24 MB
  ushort* Wob   = (ushort*)(ws + 32 * MB);
  float*  qpre  = (float*)(ws + 40 * MB);    // 16 MB
  float*  kpre  = (float*)(ws + 56 * MB);    // 16 MB
  ushort* Qb    = (ushort*)(ws + 72 * MB);
  ushort* Kb    = (ushort*)(ws + 80 * MB);
  ushort* Vt    = (ushort*)(ws + 88 * MB);
  ushort* Ob    = (ushort*)(ws + 40 * MB);   // aliases qpre (dead after fuse)
  float*  pbuf  = (float*)(ws + 56 * MB);    // 32 MB, aliases kpre/Qb/Kb (dead by then)

  const int nx8 = (S_ * DIMc) / 8;
  const int nw8 = (DIMc * DIMc) / 8;
  const int nmax = (nx8 > nw8 ? nx8 : nw8);
  cvt5<<<dim3((nmax + 255) / 256, 5), 256, 0, stream>>>(x, Wq, Wk, Wv, Wo,
                                                        xb, Wqkvb, Wob, nx8, nw8);

  gemm_qkv_db<<<dim3(3 * DIMc / 128, S_ / 128), 512, 0, stream>>>(
      xb, Wqkvb, bq, bk, bv, qpre, kpre, Vt, DIMc, S_);

  const float foldq = LOG2E / sqrtf((float)(DIMc / 16));
  fuse_rms_rope<<<dim3(S_, 2), 256, 0, stream>>>(qpre, kpre, gq, gk, fc, fs, pH, pW,
                                                 Qb, Kb, DIMc, foldq);

  attn32<<<dim3(S_ / 128, 16), 512, 0, stream>>>(Qb, Kb, Vt, Ob, seq, S_, DIMc);

  gemm_wo_db<<<dim3(16, 16, 2), 512, 0, stream>>>(Ob, Wob, pbuf, DIMc);
  reduce_wo<<<(S_ * DIMc / 4 + 255) / 256, 256, 0, stream>>>(pbuf, bo, (float*)d_out,
                                                             S_ * DIMc / 4);
}

// Round 9
// 187.216 us; speedup vs baseline: 1.0299x; 1.0011x over previous
//
#include <hip/hip_runtime.h>
#include <cstdint>
#include <cmath>

typedef unsigned int uint;
typedef unsigned short ushort;
typedef __bf16 bf16_t;
typedef bf16_t bf16x8 __attribute__((ext_vector_type(8)));
typedef float f32x4 __attribute__((ext_vector_type(4)));
typedef float f32x16 __attribute__((ext_vector_type(16)));

#define LOG2E 1.44269504088896340736f

__device__ __forceinline__ ushort f2bf(float f) {
  uint x = __float_as_uint(f);
  x += 0x7fffu + ((x >> 16) & 1u);   // RNE to bf16
  return (ushort)(x >> 16);
}
__device__ __forceinline__ uint pack2(float lo, float hi) {
  return (uint)f2bf(lo) | ((uint)f2bf(hi) << 16);
}
__device__ __forceinline__ uint cvt_pk_bf16(float lo, float hi) {
  uint r;
  asm("v_cvt_pk_bf16_f32 %0, %1, %2" : "=v"(r) : "v"(lo), "v"(hi));
  return r;
}

// global -> LDS direct copy, 16B per lane; LDS dest is wave-uniform base + lane*16.
__device__ __forceinline__ void gload_lds16(const void* gsrc, void* ldsdst) {
  typedef const __attribute__((address_space(1))) unsigned int* gp_t;
  typedef __attribute__((address_space(3))) unsigned int* lp_t;
  __builtin_amdgcn_global_load_lds((gp_t)(uintptr_t)gsrc,
                                   (lp_t)(unsigned int)(uintptr_t)ldsdst,
                                   16, 0, 0);
}

// ---------------- fp32 -> bf16 converts: x + 4 weights in ONE launch ----------------
__global__ __launch_bounds__(256) void cvt5(const float* __restrict__ x,
                                            const float* __restrict__ wq,
                                            const float* __restrict__ wk,
                                            const float* __restrict__ wv,
                                            const float* __restrict__ wo,
                                            ushort* __restrict__ xb,
                                            ushort* __restrict__ wqkv,
                                            ushort* __restrict__ wob,
                                            int nx8, int nw8) {
  const int y = blockIdx.y;
  const float* src;
  ushort* dst;
  int n8;
  if (y == 0)      { src = x;  dst = xb;  n8 = nx8; }
  else if (y == 4) { src = wo; dst = wob; n8 = nw8; }
  else {
    src = (y == 1) ? wq : (y == 2) ? wk : wv;
    dst = wqkv + (size_t)(y - 1) * nw8 * 8;
    n8 = nw8;
  }
  int i = blockIdx.x * blockDim.x + threadIdx.x;
  if (i >= n8) return;
  const float4* s4 = (const float4*)src;
  float4 a = s4[i * 2], b = s4[i * 2 + 1];
  uint4 o;
  o.x = pack2(a.x, a.y); o.y = pack2(a.z, a.w);
  o.z = pack2(b.x, b.y); o.w = pack2(b.z, b.w);
  ((uint4*)dst)[i] = o;
}

// ---------------- fused QKV GEMM: 128(M) x 256(N) tile, 8 waves, wave tile 64x64 ------
// acc[4][4] per wave -> 8 ds_read_b128 : 16 MFMA = 32 FLOP per LDS byte (vs 21.8 in the
// 32x64 geometry that saturated the LDS read pipe at MfmaUtil 28%).
// LDS: A[2][8KB] + B[2][16KB] = 48 KB, dbuf + counted vmcnt(3) (no per-iter drain).
// Grid (24,16)=384 blocks of 512 thr -> ~1.5-2 blocks/CU co-resident.
__global__ __launch_bounds__(512) void gemm_qkv_wide(const ushort* __restrict__ A,
                                                     const ushort* __restrict__ B,
                                                     const float* __restrict__ bq,
                                                     const float* __restrict__ bk,
                                                     const float* __restrict__ bv,
                                                     float* __restrict__ qpre,
                                                     float* __restrict__ kpre,
                                                     ushort* __restrict__ Vt,
                                                     int K, int S_) {
  __shared__ __align__(16) unsigned char As[16384];   // 2 buffers x 8 KB (128x32 bf16)
  __shared__ __align__(16) unsigned char Bs[32768];   // 2 buffers x 16 KB (256x32 bf16)
  const int t = threadIdx.x, l = t & 63, w = t >> 6;
  const int g = l >> 4, c = l & 15;
  const int wr = w >> 2, wc = w & 3;          // 2(M) x 4(N) wave grid, wave tile 64x64
  const int tm = blockIdx.y * 128, tn = blockIdx.x * 256;

  const int srow = t >> 2;                    // 0..127
  const int schunk = (t & 3) ^ (srow & 3);    // pre-swizzled source chunk (16B units)
  const ushort* Ag  = A + (size_t)(tm + srow) * K + schunk * 8;
  const ushort* Bg0 = B + (size_t)(tn + srow) * K + schunk * 8;
  const ushort* Bg1 = B + (size_t)(tn + 128 + srow) * K + schunk * 8;  // (row+128)&3 == row&3

  f32x4 acc[4][4] = {};

  const int NT = K >> 5;   // 64 K-steps of 32
  // prologue: tile 0 -> buffer 0  (LDS dest t*16 == row(t>>2)*64 + chunk(t&3)*16)
  gload_lds16(Ag,  As + t * 16);
  gload_lds16(Bg0, Bs + t * 16);
  gload_lds16(Bg1, Bs + 8192 + t * 16);

  for (int j = 0; j < NT; ++j) {
    const int buf = j & 1, nb = buf ^ 1;
    if (j + 1 < NT) {
      const int kt1 = (j + 1) << 5;
      gload_lds16(Ag + kt1,  As + nb * 8192 + t * 16);
      gload_lds16(Bg0 + kt1, Bs + nb * 16384 + t * 16);
      gload_lds16(Bg1 + kt1, Bs + nb * 16384 + 8192 + t * 16);
      asm volatile("s_waitcnt vmcnt(3)" ::: "memory");   // tile j landed; j+1 in flight
    } else {
      asm volatile("s_waitcnt vmcnt(0)" ::: "memory");
    }
    __builtin_amdgcn_s_barrier();     // tile j visible to all waves

    const unsigned char* Ab = As + buf * 8192;
    const unsigned char* Bb = Bs + buf * 16384;
    bf16x8 af[4], bfr[4];
#pragma unroll
    for (int m = 0; m < 4; ++m) {
      int row = wr * 64 + m * 16 + c;
      af[m] = *(const bf16x8*)(Ab + row * 64 + ((g ^ (row & 3)) << 4));
    }
#pragma unroll
    for (int n = 0; n < 4; ++n) {
      int row = wc * 64 + n * 16 + c;
      bfr[n] = *(const bf16x8*)(Bb + row * 64 + ((g ^ (row & 3)) << 4));
    }
    __builtin_amdgcn_s_setprio(1);
#pragma unroll
    for (int m = 0; m < 4; ++m)
#pragma unroll
      for (int n = 0; n < 4; ++n)
        acc[m][n] = __builtin_amdgcn_mfma_f32_16x16x32_bf16(af[m], bfr[n], acc[m][n], 0, 0, 0);
    __builtin_amdgcn_s_setprio(0);

    __builtin_amdgcn_s_barrier();     // all reads of buf done -> j+2 may overwrite it
  }

  const int sel = tn >> 11;   // uniform per block (bx<8 -> Q, <16 -> K, else V)
  if (sel < 2) {
    float* outp = sel ? kpre : qpre;
    const float* bias = sel ? bk : bq;
#pragma unroll
    for (int n = 0; n < 4; ++n) {
      int col = (tn & 2047) + wc * 64 + n * 16 + c;
      float bvv = bias[col];
#pragma unroll
      for (int m = 0; m < 4; ++m) {
        int row0 = tm + wr * 64 + m * 16 + g * 4;
#pragma unroll
        for (int i = 0; i < 4; ++i)
          outp[(size_t)(row0 + i) * 2048 + col] = acc[m][n][i] + bvv;
      }
    }
  } else {
#pragma unroll
    for (int n = 0; n < 4; ++n) {
      int colv = (tn & 2047) + wc * 64 + n * 16 + c;
      float bvv = bv[colv];
#pragma unroll
      for (int m = 0; m < 4; ++m) {
        int row0 = tm + wr * 64 + m * 16 + g * 4;
        uint2 o;
        o.x = pack2(acc[m][n][0] + bvv, acc[m][n][1] + bvv);
        o.y = pack2(acc[m][n][2] + bvv, acc[m][n][3] + bvv);
        *(uint2*)(Vt + (size_t)colv * S_ + row0) = o;
      }
    }
  }
}

// ---------------- Wo GEMM split-K=2, 8 waves, dbuf + counted vmcnt (R8) ----------------
__global__ __launch_bounds__(512) void gemm_wo_db(const ushort* __restrict__ A,
                                                  const ushort* __restrict__ B,
                                                  float* __restrict__ pbuf, int K) {
  __shared__ __align__(16) unsigned char As[16384];
  __shared__ __align__(16) unsigned char Bs[16384];
  const int t = threadIdx.x, l = t & 63, w = t >> 6;
  const int g = l >> 4, c = l & 15;
  const int wr = w >> 1, wc = w & 1;
  const int tm = blockIdx.y * 128, tn = blockIdx.x * 128;
  const int ks = blockIdx.z;
  const int k0 = ks * (K >> 1);

  const int srow = w * 16 + (l >> 2);
  const int schunk = (l & 3) ^ (srow & 3);
  const ushort* Ag = A + (size_t)(tm + srow) * K + k0 + schunk * 8;
  const ushort* Bg = B + (size_t)(tn + srow) * K + k0 + schunk * 8;

  f32x4 acc[2][4] = {};

  const int NT = K >> 6;   // (K/2)/32 = 32 K-steps
  gload_lds16(Ag, As + w * 1024);
  gload_lds16(Bg, Bs + w * 1024);

  for (int j = 0; j < NT; ++j) {
    const int buf = j & 1, nb = buf ^ 1;
    if (j + 1 < NT) {
      const int kt1 = (j + 1) << 5;
      gload_lds16(Ag + kt1, As + nb * 8192 + w * 1024);
      gload_lds16(Bg + kt1, Bs + nb * 8192 + w * 1024);
      asm volatile("s_waitcnt vmcnt(2)" ::: "memory");
    } else {
      asm volatile("s_waitcnt vmcnt(0)" ::: "memory");
    }
    __builtin_amdgcn_s_barrier();

    const unsigned char* Ab = As + buf * 8192;
    const unsigned char* Bb = Bs + buf * 8192;
    bf16x8 af[2], bfr[4];
#pragma unroll
    for (int m = 0; m < 2; ++m) {
      int row = wr * 32 + m * 16 + c;
      af[m] = *(const bf16x8*)(Ab + row * 64 + ((g ^ (row & 3)) << 4));
    }
#pragma unroll
    for (int n = 0; n < 4; ++n) {
      int row = wc * 64 + n * 16 + c;
      bfr[n] = *(const bf16x8*)(Bb + row * 64 + ((g ^ (row & 3)) << 4));
    }
#pragma unroll
    for (int m = 0; m < 2; ++m)
#pragma unroll
      for (int n = 0; n < 4; ++n)
        acc[m][n] = __builtin_amdgcn_mfma_f32_16x16x32_bf16(af[m], bfr[n], acc[m][n], 0, 0, 0);

    __builtin_amdgcn_s_barrier();
  }

  float* out = pbuf + (size_t)ks * 2048 * 2048;
#pragma unroll
  for (int n = 0; n < 4; ++n) {
    int col = tn + wc * 64 + n * 16 + c;
#pragma unroll
    for (int m = 0; m < 2; ++m) {
      int row0 = tm + wr * 32 + m * 16 + g * 4;
#pragma unroll
      for (int i = 0; i < 4; ++i)
        out[(size_t)(row0 + i) * 2048 + col] = acc[m][n][i];
    }
  }
}

__global__ __launch_bounds__(256) void reduce_wo(const float* __restrict__ p,
                                                 const float* __restrict__ bo,
                                                 float* __restrict__ out, int n4) {
  int i = blockIdx.x * blockDim.x + threadIdx.x;
  if (i >= n4) return;
  float4 a = ((const float4*)p)[i];
  float4 b = ((const float4*)p)[i + n4];
  float4 bb = *(const float4*)(bo + ((i * 4) & 2047));
  float4 o;
  o.x = a.x + b.x + bb.x; o.y = a.y + b.y + bb.y;
  o.z = a.z + b.z + bb.z; o.w = a.w + b.w + bb.w;
  ((float4*)out)[i] = o;
}

// ---------------- fused rmsnorm + 3-axis RoPE + scale-fold, fp32 -> bf16 ----------------
__global__ __launch_bounds__(256) void fuse_rms_rope(const float* __restrict__ qpre,
                                                     const float* __restrict__ kpre,
                                                     const float* __restrict__ gq,
                                                     const float* __restrict__ gk,
                                                     const float* __restrict__ fc,
                                                     const float* __restrict__ fs,
                                                     const int* __restrict__ pH,
                                                     const int* __restrict__ pW,
                                                     ushort* __restrict__ Qb,
                                                     ushort* __restrict__ Kb,
                                                     int dim, float foldq) {
  const int which = blockIdx.y;
  const float* pre = which ? kpre : qpre;
  const float* gw = which ? gk : gq;
  ushort* outp = which ? Kb : Qb;
  const float fold = which ? 1.0f : foldq;

  const int p = blockIdx.x, t = threadIdx.x;
  const float* row = pre + (size_t)p * dim;
  float v[8];
  {
    float4 a = *(const float4*)(row + t * 8);
    float4 b = *(const float4*)(row + t * 8 + 4);
    v[0] = a.x; v[1] = a.y; v[2] = a.z; v[3] = a.w;
    v[4] = b.x; v[5] = b.y; v[6] = b.z; v[7] = b.w;
  }
  float ss = 0.f;
#pragma unroll
  for (int i = 0; i < 8; ++i) ss += v[i] * v[i];
#pragma unroll
  for (int off = 32; off; off >>= 1) ss += __shfl_xor(ss, off);
  __shared__ float wsum[4];
  if ((t & 63) == 0) wsum[t >> 6] = ss;
  __syncthreads();
  float rstd = rsqrtf((wsum[0] + wsum[1] + wsum[2] + wsum[3]) * (1.0f / dim) + 1e-6f);
  float gv[8];
  {
    float4 a = *(const float4*)(gw + t * 8);
    float4 b = *(const float4*)(gw + t * 8 + 4);
    gv[0] = a.x; gv[1] = a.y; gv[2] = a.z; gv[3] = a.w;
    gv[4] = b.x; gv[5] = b.y; gv[6] = b.z; gv[7] = b.w;
  }
#pragma unroll
  for (int i = 0; i < 8; ++i) v[i] = v[i] * rstd * gv[i];

  const int H = pH[0], W = pW[0];
  const int hw = H * W;
  const int fr = p / hw;
  const int rem = p - fr * hw;
  const int hh = rem / W;
  const int ww = rem - hh * W;
  const int hd = dim / 16;
  const int cd = hd >> 1;
  const int c2 = cd / 3, c1 = cd - 2 * c2;
  const int j0 = ((t * 8) % hd) >> 1;

  uint ob[4];
#pragma unroll
  for (int q = 0; q < 4; ++q) {
    int j = j0 + q;
    int ri = (j < c1) ? fr : ((j < c1 + c2) ? hh : ww);
    float cs = fc[ri * cd + j];
    float sn = fs[ri * cd + j];
    float a = v[2 * q], b = v[2 * q + 1];
    ob[q] = pack2((a * cs - b * sn) * fold, (a * sn + b * cs) * fold);
  }
  uint4 o4; o4.x = ob[0]; o4.y = ob[1]; o4.z = ob[2]; o4.w = ob[3];
  *(uint4*)(outp + (size_t)p * dim + t * 8) = o4;
}

// ---------------- flash attention, 32x32 MFMA, 4 q-subtiles x 2 KV-splits ----------------
__global__ __launch_bounds__(512, 2) void attn32(const ushort* __restrict__ Qb,
                                                 const ushort* __restrict__ Kb,
                                                 const ushort* __restrict__ Vt,
                                                 ushort* __restrict__ Ob,
                                                 const int* __restrict__ seq_lens,
                                                 int S_, int DIMc) {
  __shared__ __align__(16) unsigned char smem[66560];
  float* mlbuf = (float*)(smem + 65536);
  const int t = threadIdx.x, l = t & 63, w = t >> 6;
  const int qsub = w & 3, ksp = w >> 2;
  const int h = l >> 5, ql = l & 31;

  const int orig = blockIdx.y * gridDim.x + blockIdx.x;
  const int nwg = gridDim.x * gridDim.y;
  const int lin = (orig & 7) * (nwg >> 3) + (orig >> 3);
  const int q0 = (lin % gridDim.x) * 128;
  const int head = lin / gridDim.x;
  const int kvlen = seq_lens[0];

  unsigned char* sk_s = smem + ksp * 16384;
  unsigned char* sv_s = smem + 32768 + ksp * 16384;

  bf16x8 qf[8];
  {
    const ushort* qp = Qb + (size_t)(q0 + qsub * 32 + ql) * DIMc + head * 128 + h * 8;
#pragma unroll
    for (int s = 0; s < 8; ++s) qf[s] = *(const bf16x8*)(qp + s * 16);
  }

  f32x16 ofr[4] = {};
  float m_run = -1e30f, l_run = 0.f;

  const int nt = (kvlen + 63) >> 6;
  const int half = (nt + 1) >> 1;
  const int tbase = ksp ? half : 0;
  const int mycnt = ksp ? (nt - half) : half;

  for (int tt = 0; tt < half; ++tt) {
    __syncthreads();
    if (tt < mycnt) {
      const int kv0 = (tbase + tt) * 64;
#pragma unroll
      for (int it = 0; it < 4; ++it) {
        int kr = qsub * 16 + it * 4 + (l >> 4);
        int kc = (l & 15) ^ (kr & 15);
        gload_lds16(Kb + (size_t)(kv0 + kr) * DIMc + head * 128 + kc * 8,
                    sk_s + qsub * 4096 + it * 1024);
        int vr = qsub * 32 + it * 8 + (l >> 3);
        int vc = (l & 7) ^ (vr & 7);
        gload_lds16(Vt + (size_t)(head * 128 + vr) * S_ + kv0 + vc * 8,
                    sv_s + qsub * 4096 + it * 1024);
      }
    }
    __syncthreads();
    if (tt >= mycnt) continue;
    const int kv0 = (tbase + tt) * 64;

    f32x16 sfr[2] = {};
    __builtin_amdgcn_s_setprio(1);
#pragma unroll
    for (int kb = 0; kb < 2; ++kb) {
      const unsigned char* kbp = sk_s + (kb * 32 + ql) * 256;
      const int rx = (kb * 32 + ql) & 15;
#pragma unroll
      for (int s = 0; s < 8; ++s) {
        bf16x8 kf = *(const bf16x8*)(kbp + (((s * 2 + h) ^ rx) << 4));
        sfr[kb] = __builtin_amdgcn_mfma_f32_32x32x16_bf16(kf, qf[s], sfr[kb], 0, 0, 0);
      }
    }
    __builtin_amdgcn_s_setprio(0);

    if (kv0 + 64 > kvlen) {
#pragma unroll
      for (int kb = 0; kb < 2; ++kb)
#pragma unroll
        for (int r = 0; r < 16; ++r) {
          int key = kv0 + kb * 32 + (r & 3) + 8 * (r >> 2) + 4 * h;
          if (key >= kvlen) sfr[kb][r] = -1e30f;
        }
    }

    float mt = -1e30f;
#pragma unroll
    for (int kb = 0; kb < 2; ++kb)
#pragma unroll
      for (int r = 0; r < 16; ++r) mt = fmaxf(mt, sfr[kb][r]);
    mt = fmaxf(mt, __shfl_xor(mt, 32));

    if (!__all(mt <= m_run + 8.0f)) {
      float m_new = fmaxf(m_run, mt);
      float fac = __builtin_amdgcn_exp2f(m_run - m_new);
      l_run *= fac;
#pragma unroll
      for (int df = 0; df < 4; ++df) ofr[df] *= fac;
      m_run = m_new;
    }

    float ls = 0.f;
    uint u[2][4][2];
#pragma unroll
    for (int kb = 0; kb < 2; ++kb)
#pragma unroll
      for (int G = 0; G < 4; ++G) {
        float p0 = __builtin_amdgcn_exp2f(sfr[kb][G * 4 + 0] - m_run);
        float p1 = __builtin_amdgcn_exp2f(sfr[kb][G * 4 + 1] - m_run);
        float p2 = __builtin_amdgcn_exp2f(sfr[kb][G * 4 + 2] - m_run);
        float p3 = __builtin_amdgcn_exp2f(sfr[kb][G * 4 + 3] - m_run);
        ls += (p0 + p1) + (p2 + p3);
        u[kb][G][0] = cvt_pk_bf16(p0, p1);
        u[kb][G][1] = cvt_pk_bf16(p2, p3);
      }
    ls += __shfl_xor(ls, 32);
    l_run += ls;

#pragma unroll
    for (int ks = 0; ks < 4; ++ks) {
      const int kb = ks >> 1, G0 = (ks & 1) * 2;
      uint own0 = h ? u[kb][G0 + 1][0] : u[kb][G0][0];
      uint own1 = h ? u[kb][G0 + 1][1] : u[kb][G0][1];
      uint snd0 = h ? u[kb][G0][0] : u[kb][G0 + 1][0];
      uint snd1 = h ? u[kb][G0][1] : u[kb][G0 + 1][1];
      uint rcv0 = __shfl_xor(snd0, 32);
      uint rcv1 = __shfl_xor(snd1, 32);
      union { uint4 q; bf16x8 b; } uu;
      uu.q.x = h ? rcv0 : own0;
      uu.q.y = h ? rcv1 : own1;
      uu.q.z = h ? own0 : rcv0;
      uu.q.w = h ? own1 : rcv1;
      __builtin_amdgcn_s_setprio(1);
#pragma unroll
      for (int df = 0; df < 4; ++df) {
        const int row = df * 32 + ql;
        bf16x8 vf = *(const bf16x8*)(sv_s + row * 128 + (((ks * 2 + h) ^ (row & 7)) << 4));
        ofr[df] = __builtin_amdgcn_mfma_f32_32x32x16_bf16(vf, uu.b, ofr[df], 0, 0, 0);
      }
      __builtin_amdgcn_s_setprio(0);
    }
  }

  __syncthreads();
  if (ksp == 1) {
    if (h == 0) { mlbuf[qsub * 64 + ql] = m_run; mlbuf[qsub * 64 + 32 + ql] = l_run; }
    float* ob = (float*)(smem + qsub * 16384);
#pragma unroll
    for (int df = 0; df < 4; ++df)
#pragma unroll
      for (int r = 0; r < 16; ++r) {
        int d = df * 32 + (r & 3) + 8 * (r >> 2) + 4 * h;
        ob[d * 32 + ql] = ofr[df][r];
      }
  }
  __syncthreads();
  if (ksp == 0) {
    float m2 = mlbuf[qsub * 64 + ql], l2 = mlbuf[qsub * 64 + 32 + ql];
    float mstar = fmaxf(m_run, m2);
    float f1 = __builtin_amdgcn_exp2f(m_run - mstar);
    float f2 = (l2 > 0.f) ? __builtin_amdgcn_exp2f(m2 - mstar) : 0.f;
    float lstar = l_run * f1 + l2 * f2;
    float inv = 1.0f / lstar;
    float a1 = f1 * inv, a2 = f2 * inv;
    const float* ob = (const float*)(smem + qsub * 16384);
    ushort* orow = Ob + (size_t)(q0 + qsub * 32 + ql) * DIMc + head * 128;
#pragma unroll
    for (int df = 0; df < 4; ++df)
#pragma unroll
      for (int G = 0; G < 4; ++G) {
        int d0 = df * 32 + 8 * G + 4 * h;
        float v0 = ofr[df][G * 4 + 0] * a1 + ob[(d0 + 0) * 32 + ql] * a2;
        float v1 = ofr[df][G * 4 + 1] * a1 + ob[(d0 + 1) * 32 + ql] * a2;
        float v2 = ofr[df][G * 4 + 2] * a1 + ob[(d0 + 2) * 32 + ql] * a2;
        float v3 = ofr[df][G * 4 + 3] * a1 + ob[(d0 + 3) * 32 + ql] * a2;
        uint2 o; o.x = pack2(v0, v1); o.y = pack2(v2, v3);
        *(uint2*)(orow + d0) = o;
      }
  }
}

// ---------------- host ----------------
extern "C" void kernel_launch(void* const* d_in, const int* in_sizes, int n_in,
                              void* d_out, int out_size, void* d_ws, size_t ws_size,
                              hipStream_t stream) {
  const float* x  = (const float*)d_in[0];
  const float* fc = (const float*)d_in[1];
  const float* fs = (const float*)d_in[2];
  const float* Wq = (const float*)d_in[3];
  const float* bq = (const float*)d_in[4];
  const float* Wk = (const float*)d_in[5];
  const float* bk = (const float*)d_in[6];
  const float* Wv = (const float*)d_in[7];
  const float* bv = (const float*)d_in[8];
  const float* Wo = (const float*)d_in[9];
  const float* bo = (const float*)d_in[10];
  const float* gq = (const float*)d_in[11];
  const float* gk = (const float*)d_in[12];
  const int* seq  = (const int*)d_in[13];
  const int* pH   = (const int*)d_in[15];
  const int* pW   = (const int*)d_in[16];

  const int DIMc = in_sizes[4];          // 2048
  const int S_   = in_sizes[0] / DIMc;   // 2048

  char* ws = (char*)d_ws;
  const size_t MB = 1024ull * 1024ull;
  ushort* xb    = (ushort*)(ws + 0 * MB);
  ushort* Wqkvb = (ushort*)(ws + 8 * MB);    // [6144][2048] bf16 = 24 MB
  ushort* Wob   = (ushort*)(ws + 32 * MB);
  float*  qpre  = (float*)(ws + 40 * MB);    // 16 MB
  float*  kpre  = (float*)(ws + 56 * MB);    // 16 MB
  ushort* Qb    = (ushort*)(ws + 72 * MB);
  ushort* Kb    = (ushort*)(ws + 80 * MB);
  ushort* Vt    = (ushort*)(ws + 88 * MB);
  ushort* Ob    = (ushort*)(ws + 40 * MB);   // aliases qpre (dead after fuse)
  float*  pbuf  = (float*)(ws + 56 * MB);    // 32 MB, aliases kpre/Qb/Kb (dead by then)

  const int nx8 = (S_ * DIMc) / 8;
  const int nw8 = (DIMc * DIMc) / 8;
  const int nmax = (nx8 > nw8 ? nx8 : nw8);
  cvt5<<<dim3((nmax + 255) / 256, 5), 256, 0, stream>>>(x, Wq, Wk, Wv, Wo,
                                                        xb, Wqkvb, Wob, nx8, nw8);

  gemm_qkv_wide<<<dim3(3 * DIMc / 256, S_ / 128), 512, 0, stream>>>(
      xb, Wqkvb, bq, bk, bv, qpre, kpre, Vt, DIMc, S_);

  const float foldq = LOG2E / sqrtf((float)(DIMc / 16));
  fuse_rms_rope<<<dim3(S_, 2), 256, 0, stream>>>(qpre, kpre, gq, gk, fc, fs, pH, pW,
                                                 Qb, Kb, DIMc, foldq);

  attn32<<<dim3(S_ / 128, 16), 512, 0, stream>>>(Qb, Kb, Vt, Ob, seq, S_, DIMc);

  gemm_wo_db<<<dim3(16, 16, 2), 512, 0, stream>>>(Ob, Wob, pbuf, DIMc);
  reduce_wo<<<(S_ * DIMc / 4 + 255) / 256, 256, 0, stream>>>(pbuf, bo, (float*)d_out,
                                                             S_ * DIMc / 4);
}

// Round 10
// 176.492 us; speedup vs baseline: 1.0924x; 1.0608x over previous
//
#include <hip/hip_runtime.h>
#include <cstdint>
#include <cmath>

typedef unsigned int uint;
typedef unsigned short ushort;
typedef __bf16 bf16_t;
typedef bf16_t bf16x8 __attribute__((ext_vector_type(8)));
typedef float f32x4 __attribute__((ext_vector_type(4)));
typedef float f32x16 __attribute__((ext_vector_type(16)));

#define LOG2E 1.44269504088896340736f

__device__ __forceinline__ ushort f2bf(float f) {
  uint x = __float_as_uint(f);
  x += 0x7fffu + ((x >> 16) & 1u);   // RNE to bf16
  return (ushort)(x >> 16);
}
__device__ __forceinline__ uint pack2(float lo, float hi) {
  return (uint)f2bf(lo) | ((uint)f2bf(hi) << 16);
}
__device__ __forceinline__ uint cvt_pk_bf16(float lo, float hi) {
  uint r;
  asm("v_cvt_pk_bf16_f32 %0, %1, %2" : "=v"(r) : "v"(lo), "v"(hi));
  return r;
}

// global -> LDS direct copy, 16B per lane; LDS dest is wave-uniform base + lane*16.
__device__ __forceinline__ void gload_lds16(const void* gsrc, void* ldsdst) {
  typedef const __attribute__((address_space(1))) unsigned int* gp_t;
  typedef __attribute__((address_space(3))) unsigned int* lp_t;
  __builtin_amdgcn_global_load_lds((gp_t)(uintptr_t)gsrc,
                                   (lp_t)(unsigned int)(uintptr_t)ldsdst,
                                   16, 0, 0);
}

// ---------------- fp32 -> bf16 converts: x + 4 weights in ONE launch ----------------
__global__ __launch_bounds__(256) void cvt5(const float* __restrict__ x,
                                            const float* __restrict__ wq,
                                            const float* __restrict__ wk,
                                            const float* __restrict__ wv,
                                            const float* __restrict__ wo,
                                            ushort* __restrict__ xb,
                                            ushort* __restrict__ wqkv,
                                            ushort* __restrict__ wob,
                                            int nx8, int nw8) {
  const int y = blockIdx.y;
  const float* src;
  ushort* dst;
  int n8;
  if (y == 0)      { src = x;  dst = xb;  n8 = nx8; }
  else if (y == 4) { src = wo; dst = wob; n8 = nw8; }
  else {
    src = (y == 1) ? wq : (y == 2) ? wk : wv;
    dst = wqkv + (size_t)(y - 1) * nw8 * 8;
    n8 = nw8;
  }
  int i = blockIdx.x * blockDim.x + threadIdx.x;
  if (i >= n8) return;
  const float4* s4 = (const float4*)src;
  float4 a = s4[i * 2], b = s4[i * 2 + 1];
  uint4 o;
  o.x = pack2(a.x, a.y); o.y = pack2(a.z, a.w);
  o.z = pack2(b.x, b.y); o.w = pack2(b.z, b.w);
  ((uint4*)dst)[i] = o;
}

// ---------------- fused QKV GEMM: 256x256 tile, BK=64, faithful 8-phase schedule ------
// 8 waves 2(M)x4(N), per-wave 128x64 output (acc[8][4]); per phase: {ds-read subtile,
// stage ONE half-tile (2 gload_lds), barrier-wrapped 16-MFMA quadrant}; vmcnt(6) only
// at phases 4 and 8 (3 half-tiles in flight). LDS 128 KiB = [2 dbuf][2 half] x (A,B).
// Stage targets proven free >=1 barrier after last read (B/A-q0 free after P1/P5,
// A-q1 after P3/P7). Layout+swizzle byte-identical to R6's verified conflict-free one.
__global__ __launch_bounds__(512) void gemm_qkv8p(const ushort* __restrict__ A,
                                                  const ushort* __restrict__ B,
                                                  const float* __restrict__ bq,
                                                  const float* __restrict__ bk,
                                                  const float* __restrict__ bv,
                                                  float* __restrict__ qpre,
                                                  float* __restrict__ kpre,
                                                  ushort* __restrict__ Vt,
                                                  int K, int S_) {
  __shared__ __align__(16) unsigned char ldsA[65536];   // [2][2 half][128][64] bf16
  __shared__ __align__(16) unsigned char ldsB[65536];
  const int t = threadIdx.x, l = t & 63;
  const int w = t >> 6;
  const int g = l >> 4, c = l & 15;
  const int wr = w >> 2, wc = w & 3;          // 2(M) x 4(N) wave grid
  const int tm = blockIdx.y * 256, tn = blockIdx.x * 256;

  const int srow = t >> 3;                    // 0..63
  const int schunk = (t & 7) ^ (srow & 7);    // pre-swizzled source chunk
  const ushort* Ag = A + (size_t)(tm + srow) * K + schunk * 8;
  const ushort* Bg = B + (size_t)(tn + srow) * K + schunk * 8;
  const size_t rK64 = (size_t)64 * K;

  // stage one 64-row gload: matrix X in {A,B}, half h, quarter q, K-tile kt
#define STG_A(kt, h, q) gload_lds16(Ag + (size_t)(2*(h)+(q)) * rK64 + ((kt) << 6),   \
    ldsA + ((kt)&1) * 32768 + (h) * 16384 + (q) * 8192 + t * 16)
#define STG_B(kt, h, q) gload_lds16(Bg + (size_t)(2*(h)+(q)) * rK64 + ((kt) << 6),   \
    ldsB + ((kt)&1) * 32768 + (h) * 16384 + (q) * 8192 + t * 16)

  f32x4 acc[8][4] = {};
  bf16x8 af[4][2], bfr[4][2];
  const int cr = c * 128;
  const int sw0 = ((0 * 4 + g) ^ (c & 7)) << 4;
  const int sw1 = ((1 * 4 + g) ^ (c & 7)) << 4;

#define RDA(d, QM) do {                                                              \
    _Pragma("unroll") for (int mm = 0; mm < 4; ++mm) {                               \
      const unsigned char* p_ = ldsA + (d)*32768 + wr*16384 + (QM)*8192 + mm*2048 + cr; \
      af[mm][0] = *(const bf16x8*)(p_ + sw0);                                        \
      af[mm][1] = *(const bf16x8*)(p_ + sw1); }                                      \
  } while (0)
#define RDB(d) do {                                                                  \
    _Pragma("unroll") for (int nn = 0; nn < 4; ++nn) {                               \
      const unsigned char* p_ = ldsB + (d)*32768 + (wc>>1)*16384 + (wc&1)*8192 + nn*2048 + cr; \
      bfr[nn][0] = *(const bf16x8*)(p_ + sw0);                                       \
      bfr[nn][1] = *(const bf16x8*)(p_ + sw1); }                                     \
  } while (0)
#define MM(QM, QN) do {                                                              \
    __builtin_amdgcn_s_setprio(1);                                                   \
    _Pragma("unroll") for (int mm = 0; mm < 4; ++mm)                                 \
    _Pragma("unroll") for (int nn = 0; nn < 2; ++nn) {                               \
      acc[(QM)*4+mm][(QN)*2+nn] = __builtin_amdgcn_mfma_f32_16x16x32_bf16(           \
          af[mm][0], bfr[(QN)*2+nn][0], acc[(QM)*4+mm][(QN)*2+nn], 0, 0, 0);         \
      acc[(QM)*4+mm][(QN)*2+nn] = __builtin_amdgcn_mfma_f32_16x16x32_bf16(           \
          af[mm][1], bfr[(QN)*2+nn][1], acc[(QM)*4+mm][(QN)*2+nn], 0, 0, 0); }       \
    __builtin_amdgcn_s_setprio(0);                                                   \
  } while (0)
#define BAR() __builtin_amdgcn_s_barrier()

  // prologue: kt0 fully (8 loads) + kt1 {B-h0, B-h1, A-q0} (6 loads); kt1 A-q1 at P1.
  STG_B(0, 0, 0); STG_B(0, 0, 1); STG_B(0, 1, 0); STG_B(0, 1, 1);
  STG_A(0, 0, 0); STG_A(0, 1, 0); STG_A(0, 0, 1); STG_A(0, 1, 1);
  STG_B(1, 0, 0); STG_B(1, 0, 1); STG_B(1, 1, 0); STG_B(1, 1, 1);
  STG_A(1, 0, 0); STG_A(1, 1, 0);
  asm volatile("s_waitcnt vmcnt(6)" ::: "memory");
  BAR();

  const int NITER = K >> 7;   // 16 iterations x 2 K-tiles
  for (int i = 0; i < NITER; ++i) {
    const int k1 = 2 * i + 1, k2 = 2 * i + 2, k3 = 2 * i + 3;
    const bool st = (i + 1 < NITER);
    // P1: read kt2i {A-QM0, B-all}; stage kt(2i+1) A-q1 -> dbuf1
    RDA(0, 0); RDB(0);
    STG_A(k1, 0, 1); STG_A(k1, 1, 1);
    MM(0, 0); BAR();
    // P2: stage kt(2i+2) B-h0 -> dbuf0 (B free since P1)
    if (st) { STG_B(k2, 0, 0); STG_B(k2, 0, 1); }
    MM(0, 1); BAR();
    // P3: read kt2i A-QM1; stage kt(2i+2) B-h1
    RDA(0, 1);
    if (st) { STG_B(k2, 1, 0); STG_B(k2, 1, 1); }
    MM(1, 0); BAR();
    // P4: stage kt(2i+2) A-q0 (free since P1); vmcnt(6) completes kt(2i+1)
    if (st) { STG_A(k2, 0, 0); STG_A(k2, 1, 0); }
    MM(1, 1);
    if (st) asm volatile("s_waitcnt vmcnt(6)" ::: "memory");
    else    asm volatile("s_waitcnt vmcnt(0)" ::: "memory");
    BAR();
    // P5: read kt(2i+1) {A-QM0, B-all}; stage kt(2i+2) A-q1 (free since P3)
    RDA(1, 0); RDB(1);
    if (st) { STG_A(k2, 0, 1); STG_A(k2, 1, 1); }
    MM(0, 0); BAR();
    // P6: stage kt(2i+3) B-h0 -> dbuf1 (B free since P5)
    if (st) { STG_B(k3, 0, 0); STG_B(k3, 0, 1); }
    MM(0, 1); BAR();
    // P7: read kt(2i+1) A-QM1; stage kt(2i+3) B-h1
    RDA(1, 1);
    if (st) { STG_B(k3, 1, 0); STG_B(k3, 1, 1); }
    MM(1, 0); BAR();
    // P8: stage kt(2i+3) A-q0 (free since P5); vmcnt(6) completes kt(2i+2)
    if (st) { STG_A(k3, 0, 0); STG_A(k3, 1, 0); }
    MM(1, 1);
    if (st) asm volatile("s_waitcnt vmcnt(6)" ::: "memory");
    else    asm volatile("s_waitcnt vmcnt(0)" ::: "memory");
    BAR();
  }

#undef STG_A
#undef STG_B
#undef RDA
#undef RDB
#undef MM
#undef BAR

  const int sel = tn >> 11;   // uniform per block (2048 % 256 == 0)
  if (sel < 2) {
    float* outp = sel ? kpre : qpre;
    const float* bias = sel ? bk : bq;
#pragma unroll
    for (int n = 0; n < 4; ++n) {
      int col = (tn & 2047) + wc * 64 + n * 16 + c;
      float bvv = bias[col];
#pragma unroll
      for (int m = 0; m < 8; ++m) {
        int row0 = tm + wr * 128 + m * 16 + g * 4;
#pragma unroll
        for (int i = 0; i < 4; ++i)
          outp[(size_t)(row0 + i) * 2048 + col] = acc[m][n][i] + bvv;
      }
    }
  } else {
#pragma unroll
    for (int n = 0; n < 4; ++n) {
      int colv = (tn - 4096) + wc * 64 + n * 16 + c;
      float bvv = bv[colv];
#pragma unroll
      for (int m = 0; m < 8; ++m) {
        int row0 = tm + wr * 128 + m * 16 + g * 4;
        uint2 o;
        o.x = pack2(acc[m][n][0] + bvv, acc[m][n][1] + bvv);
        o.y = pack2(acc[m][n][2] + bvv, acc[m][n][3] + bvv);
        *(uint2*)(Vt + (size_t)colv * S_ + row0) = o;
      }
    }
  }
}

// ---------------- Wo GEMM split-K=2, 8 waves, dbuf + counted vmcnt (R8) ----------------
__global__ __launch_bounds__(512) void gemm_wo_db(const ushort* __restrict__ A,
                                                  const ushort* __restrict__ B,
                                                  float* __restrict__ pbuf, int K) {
  __shared__ __align__(16) unsigned char As[16384];
  __shared__ __align__(16) unsigned char Bs[16384];
  const int t = threadIdx.x, l = t & 63, w = t >> 6;
  const int g = l >> 4, c = l & 15;
  const int wr = w >> 1, wc = w & 1;
  const int tm = blockIdx.y * 128, tn = blockIdx.x * 128;
  const int ks = blockIdx.z;
  const int k0 = ks * (K >> 1);

  const int srow = w * 16 + (l >> 2);
  const int schunk = (l & 3) ^ (srow & 3);
  const ushort* Ag = A + (size_t)(tm + srow) * K + k0 + schunk * 8;
  const ushort* Bg = B + (size_t)(tn + srow) * K + k0 + schunk * 8;

  f32x4 acc[2][4] = {};

  const int NT = K >> 6;   // (K/2)/32 = 32 K-steps
  gload_lds16(Ag, As + w * 1024);
  gload_lds16(Bg, Bs + w * 1024);

  for (int j = 0; j < NT; ++j) {
    const int buf = j & 1, nb = buf ^ 1;
    if (j + 1 < NT) {
      const int kt1 = (j + 1) << 5;
      gload_lds16(Ag + kt1, As + nb * 8192 + w * 1024);
      gload_lds16(Bg + kt1, Bs + nb * 8192 + w * 1024);
      asm volatile("s_waitcnt vmcnt(2)" ::: "memory");
    } else {
      asm volatile("s_waitcnt vmcnt(0)" ::: "memory");
    }
    __builtin_amdgcn_s_barrier();

    const unsigned char* Ab = As + buf * 8192;
    const unsigned char* Bb = Bs + buf * 8192;
    bf16x8 af[2], bfr[4];
#pragma unroll
    for (int m = 0; m < 2; ++m) {
      int row = wr * 32 + m * 16 + c;
      af[m] = *(const bf16x8*)(Ab + row * 64 + ((g ^ (row & 3)) << 4));
    }
#pragma unroll
    for (int n = 0; n < 4; ++n) {
      int row = wc * 64 + n * 16 + c;
      bfr[n] = *(const bf16x8*)(Bb + row * 64 + ((g ^ (row & 3)) << 4));
    }
#pragma unroll
    for (int m = 0; m < 2; ++m)
#pragma unroll
      for (int n = 0; n < 4; ++n)
        acc[m][n] = __builtin_amdgcn_mfma_f32_16x16x32_bf16(af[m], bfr[n], acc[m][n], 0, 0, 0);

    __builtin_amdgcn_s_barrier();
  }

  float* out = pbuf + (size_t)ks * 2048 * 2048;
#pragma unroll
  for (int n = 0; n < 4; ++n) {
    int col = tn + wc * 64 + n * 16 + c;
#pragma unroll
    for (int m = 0; m < 2; ++m) {
      int row0 = tm + wr * 32 + m * 16 + g * 4;
#pragma unroll
      for (int i = 0; i < 4; ++i)
        out[(size_t)(row0 + i) * 2048 + col] = acc[m][n][i];
    }
  }
}

__global__ __launch_bounds__(256) void reduce_wo(const float* __restrict__ p,
                                                 const float* __restrict__ bo,
                                                 float* __restrict__ out, int n4) {
  int i = blockIdx.x * blockDim.x + threadIdx.x;
  if (i >= n4) return;
  float4 a = ((const float4*)p)[i];
  float4 b = ((const float4*)p)[i + n4];
  float4 bb = *(const float4*)(bo + ((i * 4) & 2047));
  float4 o;
  o.x = a.x + b.x + bb.x; o.y = a.y + b.y + bb.y;
  o.z = a.z + b.z + bb.z; o.w = a.w + b.w + bb.w;
  ((float4*)out)[i] = o;
}

// ---------------- fused rmsnorm + 3-axis RoPE + scale-fold, fp32 -> bf16 ----------------
__global__ __launch_bounds__(256) void fuse_rms_rope(const float* __restrict__ qpre,
                                                     const float* __restrict__ kpre,
                                                     const float* __restrict__ gq,
                                                     const float* __restrict__ gk,
                                                     const float* __restrict__ fc,
                                                     const float* __restrict__ fs,
                                                     const int* __restrict__ pH,
                                                     const int* __restrict__ pW,
                                                     ushort* __restrict__ Qb,
                                                     ushort* __restrict__ Kb,
                                                     int dim, float foldq) {
  const int which = blockIdx.y;
  const float* pre = which ? kpre : qpre;
  const float* gw = which ? gk : gq;
  ushort* outp = which ? Kb : Qb;
  const float fold = which ? 1.0f : foldq;

  const int p = blockIdx.x, t = threadIdx.x;
  const float* row = pre + (size_t)p * dim;
  float v[8];
  {
    float4 a = *(const float4*)(row + t * 8);
    float4 b = *(const float4*)(row + t * 8 + 4);
    v[0] = a.x; v[1] = a.y; v[2] = a.z; v[3] = a.w;
    v[4] = b.x; v[5] = b.y; v[6] = b.z; v[7] = b.w;
  }
  float ss = 0.f;
#pragma unroll
  for (int i = 0; i < 8; ++i) ss += v[i] * v[i];
#pragma unroll
  for (int off = 32; off; off >>= 1) ss += __shfl_xor(ss, off);
  __shared__ float wsum[4];
  if ((t & 63) == 0) wsum[t >> 6] = ss;
  __syncthreads();
  float rstd = rsqrtf((wsum[0] + wsum[1] + wsum[2] + wsum[3]) * (1.0f / dim) + 1e-6f);
  float gv[8];
  {
    float4 a = *(const float4*)(gw + t * 8);
    float4 b = *(const float4*)(gw + t * 8 + 4);
    gv[0] = a.x; gv[1] = a.y; gv[2] = a.z; gv[3] = a.w;
    gv[4] = b.x; gv[5] = b.y; gv[6] = b.z; gv[7] = b.w;
  }
#pragma unroll
  for (int i = 0; i < 8; ++i) v[i] = v[i] * rstd * gv[i];

  const int H = pH[0], W = pW[0];
  const int hw = H * W;
  const int fr = p / hw;
  const int rem = p - fr * hw;
  const int hh = rem / W;
  const int ww = rem - hh * W;
  const int hd = dim / 16;
  const int cd = hd >> 1;
  const int c2 = cd / 3, c1 = cd - 2 * c2;
  const int j0 = ((t * 8) % hd) >> 1;

  uint ob[4];
#pragma unroll
  for (int q = 0; q < 4; ++q) {
    int j = j0 + q;
    int ri = (j < c1) ? fr : ((j < c1 + c2) ? hh : ww);
    float cs = fc[ri * cd + j];
    float sn = fs[ri * cd + j];
    float a = v[2 * q], b = v[2 * q + 1];
    ob[q] = pack2((a * cs - b * sn) * fold, (a * sn + b * cs) * fold);
  }
  uint4 o4; o4.x = ob[0]; o4.y = ob[1]; o4.z = ob[2]; o4.w = ob[3];
  *(uint4*)(outp + (size_t)p * dim + t * 8) = o4;
}

// ---------------- flash attention, 32x32 MFMA, 4 q-subtiles x 2 KV-splits ----------------
__global__ __launch_bounds__(512, 2) void attn32(const ushort* __restrict__ Qb,
                                                 const ushort* __restrict__ Kb,
                                                 const ushort* __restrict__ Vt,
                                                 ushort* __restrict__ Ob,
                                                 const int* __restrict__ seq_lens,
                                                 int S_, int DIMc) {
  __shared__ __align__(16) unsigned char smem[66560];
  float* mlbuf = (float*)(smem + 65536);
  const int t = threadIdx.x, l = t & 63, w = t >> 6;
  const int qsub = w & 3, ksp = w >> 2;
  const int h = l >> 5, ql = l & 31;

  const int orig = blockIdx.y * gridDim.x + blockIdx.x;
  const int nwg = gridDim.x * gridDim.y;
  const int lin = (orig & 7) * (nwg >> 3) + (orig >> 3);
  const int q0 = (lin % gridDim.x) * 128;
  const int head = lin / gridDim.x;
  const int kvlen = seq_lens[0];

  unsigned char* sk_s = smem + ksp * 16384;
  unsigned char* sv_s = smem + 32768 + ksp * 16384;

  bf16x8 qf[8];
  {
    const ushort* qp = Qb + (size_t)(q0 + qsub * 32 + ql) * DIMc + head * 128 + h * 8;
#pragma unroll
    for (int s = 0; s < 8; ++s) qf[s] = *(const bf16x8*)(qp + s * 16);
  }

  f32x16 ofr[4] = {};
  float m_run = -1e30f, l_run = 0.f;

  const int nt = (kvlen + 63) >> 6;
  const int half = (nt + 1) >> 1;
  const int tbase = ksp ? half : 0;
  const int mycnt = ksp ? (nt - half) : half;

  for (int tt = 0; tt < half; ++tt) {
    __syncthreads();
    if (tt < mycnt) {
      const int kv0 = (tbase + tt) * 64;
#pragma unroll
      for (int it = 0; it < 4; ++it) {
        int kr = qsub * 16 + it * 4 + (l >> 4);
        int kc = (l & 15) ^ (kr & 15);
        gload_lds16(Kb + (size_t)(kv0 + kr) * DIMc + head * 128 + kc * 8,
                    sk_s + qsub * 4096 + it * 1024);
        int vr = qsub * 32 + it * 8 + (l >> 3);
        int vc = (l & 7) ^ (vr & 7);
        gload_lds16(Vt + (size_t)(head * 128 + vr) * S_ + kv0 + vc * 8,
                    sv_s + qsub * 4096 + it * 1024);
      }
    }
    __syncthreads();
    if (tt >= mycnt) continue;
    const int kv0 = (tbase + tt) * 64;

    f32x16 sfr[2] = {};
    __builtin_amdgcn_s_setprio(1);
#pragma unroll
    for (int kb = 0; kb < 2; ++kb) {
      const unsigned char* kbp = sk_s + (kb * 32 + ql) * 256;
      const int rx = (kb * 32 + ql) & 15;
#pragma unroll
      for (int s = 0; s < 8; ++s) {
        bf16x8 kf = *(const bf16x8*)(kbp + (((s * 2 + h) ^ rx) << 4));
        sfr[kb] = __builtin_amdgcn_mfma_f32_32x32x16_bf16(kf, qf[s], sfr[kb], 0, 0, 0);
      }
    }
    __builtin_amdgcn_s_setprio(0);

    if (kv0 + 64 > kvlen) {
#pragma unroll
      for (int kb = 0; kb < 2; ++kb)
#pragma unroll
        for (int r = 0; r < 16; ++r) {
          int key = kv0 + kb * 32 + (r & 3) + 8 * (r >> 2) + 4 * h;
          if (key >= kvlen) sfr[kb][r] = -1e30f;
        }
    }

    float mt = -1e30f;
#pragma unroll
    for (int kb = 0; kb < 2; ++kb)
#pragma unroll
      for (int r = 0; r < 16; ++r) mt = fmaxf(mt, sfr[kb][r]);
    mt = fmaxf(mt, __shfl_xor(mt, 32));

    if (!__all(mt <= m_run + 8.0f)) {
      float m_new = fmaxf(m_run, mt);
      float fac = __builtin_amdgcn_exp2f(m_run - m_new);
      l_run *= fac;
#pragma unroll
      for (int df = 0; df < 4; ++df) ofr[df] *= fac;
      m_run = m_new;
    }

    float ls = 0.f;
    uint u[2][4][2];
#pragma unroll
    for (int kb = 0; kb < 2; ++kb)
#pragma unroll
      for (int G = 0; G < 4; ++G) {
        float p0 = __builtin_amdgcn_exp2f(sfr[kb][G * 4 + 0] - m_run);
        float p1 = __builtin_amdgcn_exp2f(sfr[kb][G * 4 + 1] - m_run);
        float p2 = __builtin_amdgcn_exp2f(sfr[kb][G * 4 + 2] - m_run);
        float p3 = __builtin_amdgcn_exp2f(sfr[kb][G * 4 + 3] - m_run);
        ls += (p0 + p1) + (p2 + p3);
        u[kb][G][0] = cvt_pk_bf16(p0, p1);
        u[kb][G][1] = cvt_pk_bf16(p2, p3);
      }
    ls += __shfl_xor(ls, 32);
    l_run += ls;

#pragma unroll
    for (int ks = 0; ks < 4; ++ks) {
      const int kb = ks >> 1, G0 = (ks & 1) * 2;
      uint own0 = h ? u[kb][G0 + 1][0] : u[kb][G0][0];
      uint own1 = h ? u[kb][G0 + 1][1] : u[kb][G0][1];
      uint snd0 = h ? u[kb][G0][0] : u[kb][G0 + 1][0];
      uint snd1 = h ? u[kb][G0][1] : u[kb][G0 + 1][1];
      uint rcv0 = __shfl_xor(snd0, 32);
      uint rcv1 = __shfl_xor(snd1, 32);
      union { uint4 q; bf16x8 b; } uu;
      uu.q.x = h ? rcv0 : own0;
      uu.q.y = h ? rcv1 : own1;
      uu.q.z = h ? own0 : rcv0;
      uu.q.w = h ? own1 : rcv1;
      __builtin_amdgcn_s_setprio(1);
#pragma unroll
      for (int df = 0; df < 4; ++df) {
        const int row = df * 32 + ql;
        bf16x8 vf = *(const bf16x8*)(sv_s + row * 128 + (((ks * 2 + h) ^ (row & 7)) << 4));
        ofr[df] = __builtin_amdgcn_mfma_f32_32x32x16_bf16(vf, uu.b, ofr[df], 0, 0, 0);
      }
      __builtin_amdgcn_s_setprio(0);
    }
  }

  __syncthreads();
  if (ksp == 1) {
    if (h == 0) { mlbuf[qsub * 64 + ql] = m_run; mlbuf[qsub * 64 + 32 + ql] = l_run; }
    float* ob = (float*)(smem + qsub * 16384);
#pragma unroll
    for (int df = 0; df < 4; ++df)
#pragma unroll
      for (int r = 0; r < 16; ++r) {
        int d = df * 32 + (r & 3) + 8 * (r >> 2) + 4 * h;
        ob[d * 32 + ql] = ofr[df][r];
      }
  }
  __syncthreads();
  if (ksp == 0) {
    float m2 = mlbuf[qsub * 64 + ql], l2 = mlbuf[qsub * 64 + 32 + ql];
    float mstar = fmaxf(m_run, m2);
    float f1 = __builtin_amdgcn_exp2f(m_run - mstar);
    float f2 = (l2 > 0.f) ? __builtin_amdgcn_exp2f(m2 - mstar) : 0.f;
    float lstar = l_run * f1 + l2 * f2;
    float inv = 1.0f / lstar;
    float a1 = f1 * inv, a2 = f2 * inv;
    const float* ob = (const float*)(smem + qsub * 16384);
    ushort* orow = Ob + (size_t)(q0 + qsub * 32 + ql) * DIMc + head * 128;
#pragma unroll
    for (int df = 0; df < 4; ++df)
#pragma unroll
      for (int G = 0; G < 4; ++G) {
        int d0 = df * 32 + 8 * G + 4 * h;
        float v0 = ofr[df][G * 4 + 0] * a1 + ob[(d0 + 0) * 32 + ql] * a2;
        float v1 = ofr[df][G * 4 + 1] * a1 + ob[(d0 + 1) * 32 + ql] * a2;
        float v2 = ofr[df][G * 4 + 2] * a1 + ob[(d0 + 2) * 32 + ql] * a2;
        float v3 = ofr[df][G * 4 + 3] * a1 + ob[(d0 + 3) * 32 + ql] * a2;
        uint2 o; o.x = pack2(v0, v1); o.y = pack2(v2, v3);
        *(uint2*)(orow + d0) = o;
      }
  }
}

// ---------------- host ----------------
extern "C" void kernel_launch(void* const* d_in, const int* in_sizes, int n_in,
                              void* d_out, int out_size, void* d_ws, size_t ws_size,
                              hipStream_t stream) {
  const float* x  = (const float*)d_in[0];
  const float* fc = (const float*)d_in[1];
  const float* fs = (const float*)d_in[2];
  const float* Wq = (const float*)d_in[3];
  const float* bq = (const float*)d_in[4];
  const float* Wk = (const float*)d_in[5];
  const float* bk = (const float*)d_in[6];
  const float* Wv = (const float*)d_in[7];
  const float* bv = (const float*)d_in[8];
  const float* Wo = (const float*)d_in[9];
  const float* bo = (const float*)d_in[10];
  const float* gq = (const float*)d_in[11];
  const float* gk = (const float*)d_in[12];
  const int* seq  = (const int*)d_in[13];
  const int* pH   = (const int*)d_in[15];
  const int* pW   = (const int*)d_in[16];

  const int DIMc = in_sizes[4];          // 2048
  const int S_   = in_sizes[0] / DIMc;   // 2048

  char* ws = (char*)d_ws;
  const size_t MB = 1024ull * 1024ull;
  ushort* xb    = (ushort*)(ws + 0 * MB);
  ushort* Wqkvb = (ushort*)(ws + 8 * MB);    // [6144][2048] bf16 = 24 MB
  ushort* Wob   = (ushort*)(ws + 32 * MB);
  float*  qpre  = (float*)(ws + 40 * MB);    // 16 MB
  float*  kpre  = (float*)(ws + 56 * MB);    // 16 MB
  ushort* Qb    = (ushort*)(ws + 72 * MB);
  ushort* Kb    = (ushort*)(ws + 80 * MB);
  ushort* Vt    = (ushort*)(ws + 88 * MB);
  ushort* Ob    = (ushort*)(ws + 40 * MB);   // aliases qpre (dead after fuse)
  float*  pbuf  = (float*)(ws + 56 * MB);    // 32 MB, aliases kpre/Qb/Kb (dead by then)

  const int nx8 = (S_ * DIMc) / 8;
  const int nw8 = (DIMc * DIMc) / 8;
  const int nmax = (nx8 > nw8 ? nx8 : nw8);
  cvt5<<<dim3((nmax + 255) / 256, 5), 256, 0, stream>>>(x, Wq, Wk, Wv, Wo,
                                                        xb, Wqkvb, Wob, nx8, nw8);

  gemm_qkv8p<<<dim3(3 * DIMc / 256, S_ / 256), 512, 0, stream>>>(
      xb, Wqkvb, bq, bk, bv, qpre, kpre, Vt, DIMc, S_);

  const float foldq = LOG2E / sqrtf((float)(DIMc / 16));
  fuse_rms_rope<<<dim3(S_, 2), 256, 0, stream>>>(qpre, kpre, gq, gk, fc, fs, pH, pW,
                                                 Qb, Kb, DIMc, foldq);

  attn32<<<dim3(S_ / 128, 16), 512, 0, stream>>>(Qb, Kb, Vt, Ob, seq, S_, DIMc);

  gemm_wo_db<<<dim3(16, 16, 2), 512, 0, stream>>>(Ob, Wob, pbuf, DIMc);
  reduce_wo<<<(S_ * DIMc / 4 + 255) / 256, 256, 0, stream>>>(pbuf, bo, (float*)d_out,
                                                             S_ * DIMc / 4);
}

// Round 11
// 172.221 us; speedup vs baseline: 1.1195x; 1.0248x over previous
//
#include <hip/hip_runtime.h>
#include <cstdint>
#include <cmath>

typedef unsigned int uint;
typedef unsigned short ushort;
typedef __bf16 bf16_t;
typedef bf16_t bf16x8 __attribute__((ext_vector_type(8)));
typedef float f32x4 __attribute__((ext_vector_type(4)));
typedef float f32x16 __attribute__((ext_vector_type(16)));

#define LOG2E 1.44269504088896340736f

__device__ __forceinline__ ushort f2bf(float f) {
  uint x = __float_as_uint(f);
  x += 0x7fffu + ((x >> 16) & 1u);   // RNE to bf16
  return (ushort)(x >> 16);
}
__device__ __forceinline__ uint pack2(float lo, float hi) {
  return (uint)f2bf(lo) | ((uint)f2bf(hi) << 16);
}
__device__ __forceinline__ uint cvt_pk_bf16(float lo, float hi) {
  uint r;
  asm("v_cvt_pk_bf16_f32 %0, %1, %2" : "=v"(r) : "v"(lo), "v"(hi));
  return r;
}

// global -> LDS direct copy, 16B per lane; LDS dest is wave-uniform base + lane*16.
__device__ __forceinline__ void gload_lds16(const void* gsrc, void* ldsdst) {
  typedef const __attribute__((address_space(1))) unsigned int* gp_t;
  typedef __attribute__((address_space(3))) unsigned int* lp_t;
  __builtin_amdgcn_global_load_lds((gp_t)(uintptr_t)gsrc,
                                   (lp_t)(unsigned int)(uintptr_t)ldsdst,
                                   16, 0, 0);
}

// ---------------- fp32 -> bf16 converts: x + 4 weights in ONE launch ----------------
__global__ __launch_bounds__(256) void cvt5(const float* __restrict__ x,
                                            const float* __restrict__ wq,
                                            const float* __restrict__ wk,
                                            const float* __restrict__ wv,
                                            const float* __restrict__ wo,
                                            ushort* __restrict__ xb,
                                            ushort* __restrict__ wqkv,
                                            ushort* __restrict__ wob,
                                            int nx8, int nw8) {
  const int y = blockIdx.y;
  const float* src;
  ushort* dst;
  int n8;
  if (y == 0)      { src = x;  dst = xb;  n8 = nx8; }
  else if (y == 4) { src = wo; dst = wob; n8 = nw8; }
  else {
    src = (y == 1) ? wq : (y == 2) ? wk : wv;
    dst = wqkv + (size_t)(y - 1) * nw8 * 8;
    n8 = nw8;
  }
  int i = blockIdx.x * blockDim.x + threadIdx.x;
  if (i >= n8) return;
  const float4* s4 = (const float4*)src;
  float4 a = s4[i * 2], b = s4[i * 2 + 1];
  uint4 o;
  o.x = pack2(a.x, a.y); o.y = pack2(a.z, a.w);
  o.z = pack2(b.x, b.y); o.w = pack2(b.z, b.w);
  ((uint4*)dst)[i] = o;
}

// ---------------- fused QKV GEMM: 256(M) x 192(N) tile, BK=64, 8-phase schedule ------
// Grid (32,8) = 256 blocks = EXACTLY 1 block/CU (R10's 256x256 gave 192 blocks = 25% CUs
// idle). 8 waves 2(M)x4(N), per-wave 128x48 (acc[8][3]); 4 M-quarter phases x 12 MFMA
// per K-tile. 7 loads/K-tile: A units u0..3 (64 rows each), B units u0..2.
// Stage units U1{B0,B1} U2{B2,A0} U3{A1,A2} U4{A3}; placement gives every region >=1
// barrier after its last read (B free after P1; A-quarter q after P(q+1)).
// vmcnt ledger (outstanding counts walked): prologue 13 -> vmcnt(6); P4: 7 -> vmcnt(6)
// retires k(2i+1).U4; P8: 13 -> vmcnt(6) retires kt(2i+2)'s 7; steady state 6. LDS 112KB.
__global__ __launch_bounds__(512) void gemm_qkv192(const ushort* __restrict__ A,
                                                   const ushort* __restrict__ B,
                                                   const float* __restrict__ bq,
                                                   const float* __restrict__ bk,
                                                   const float* __restrict__ bv,
                                                   float* __restrict__ qpre,
                                                   float* __restrict__ kpre,
                                                   ushort* __restrict__ Vt,
                                                   int K, int S_) {
  __shared__ __align__(16) unsigned char ldsA[65536];   // [2][256 rows][64] bf16
  __shared__ __align__(16) unsigned char ldsB[49152];   // [2][192 rows][64] bf16
  const int t = threadIdx.x, l = t & 63;
  const int w = t >> 6;
  const int g = l >> 4, c = l & 15;
  const int wr = w >> 2, wc = w & 3;          // 2(M) x 4(N) wave grid
  const int tm = blockIdx.y * 256, tn = blockIdx.x * 192;

  const int srow = t >> 3;                    // 0..63
  const int schunk = (t & 7) ^ (srow & 7);    // pre-swizzled source chunk
  const ushort* Ag = A + (size_t)(tm + srow) * K + schunk * 8;
  const ushort* Bg = B + (size_t)(tn + srow) * K + schunk * 8;
  const size_t rK64 = (size_t)64 * K;

#define STG_A(kt, u) gload_lds16(Ag + (size_t)(u) * rK64 + ((kt) << 6),   \
    ldsA + ((kt)&1) * 32768 + (u) * 8192 + t * 16)
#define STG_B(kt, u) gload_lds16(Bg + (size_t)(u) * rK64 + ((kt) << 6),   \
    ldsB + ((kt)&1) * 24576 + (u) * 8192 + t * 16)

  f32x4 acc[8][3] = {};
  bf16x8 af[2][2], bfr[3][2];
  const int cr = c * 128;
  const int sw0 = ((0 * 4 + g) ^ (c & 7)) << 4;
  const int sw1 = ((1 * 4 + g) ^ (c & 7)) << 4;

  // read A M-quarter q (frags 2q, 2q+1) of dbuf d
#define RDA(d, q) do {                                                               \
    _Pragma("unroll") for (int mm = 0; mm < 2; ++mm) {                               \
      const unsigned char* p_ = ldsA + (d)*32768 + (wr*128 + (q)*32 + mm*16)*128 + cr; \
      af[mm][0] = *(const bf16x8*)(p_ + sw0);                                        \
      af[mm][1] = *(const bf16x8*)(p_ + sw1); }                                      \
  } while (0)
#define RDB(d) do {                                                                 \
    _Pragma("unroll") for (int nn = 0; nn < 3; ++nn) {                              \
      const unsigned char* p_ = ldsB + (d)*24576 + (wc*48 + nn*16)*128 + cr;        \
      bfr[nn][0] = *(const bf16x8*)(p_ + sw0);                                      \
      bfr[nn][1] = *(const bf16x8*)(p_ + sw1); }                                    \
  } while (0)
#define MM(q) do {                                                                  \
    __builtin_amdgcn_s_setprio(1);                                                  \
    _Pragma("unroll") for (int mm = 0; mm < 2; ++mm)                                \
    _Pragma("unroll") for (int nn = 0; nn < 3; ++nn) {                              \
      acc[(q)*2+mm][nn] = __builtin_amdgcn_mfma_f32_16x16x32_bf16(                  \
          af[mm][0], bfr[nn][0], acc[(q)*2+mm][nn], 0, 0, 0);                       \
      acc[(q)*2+mm][nn] = __builtin_amdgcn_mfma_f32_16x16x32_bf16(                  \
          af[mm][1], bfr[nn][1], acc[(q)*2+mm][nn], 0, 0, 0); }                     \
    __builtin_amdgcn_s_setprio(0);                                                  \
  } while (0)
#define BAR() __builtin_amdgcn_s_barrier()

  // prologue: kt0 full (7 loads) + kt1 U1-U3 (6 loads) = 13; vmcnt(6) -> kt0 landed.
  STG_B(0, 0); STG_B(0, 1); STG_B(0, 2);
  STG_A(0, 0); STG_A(0, 1); STG_A(0, 2); STG_A(0, 3);
  STG_B(1, 0); STG_B(1, 1); STG_B(1, 2);
  STG_A(1, 0); STG_A(1, 1); STG_A(1, 2);
  asm volatile("s_waitcnt vmcnt(6)" ::: "memory");
  BAR();

  const int NITER = K >> 7;   // 16 iterations x 2 K-tiles
  for (int i = 0; i < NITER; ++i) {
    const int k1 = 2 * i + 1, k2 = 2 * i + 2, k3 = 2 * i + 3;
    const bool st = (i + 1 < NITER);
    // P1: read kt(2i) {A-q0, B-all} from dbuf0; stage kt(2i+1).U4 (A3 -> dbuf1)
    RDA(0, 0); RDB(0);
    STG_A(k1, 3);
    MM(0); BAR();
    // P2: read A-q1; stage kt(2i+2).U1 {B0,B1} (dbuf0 B free since P1)
    RDA(0, 1);
    if (st) { STG_B(k2, 0); STG_B(k2, 1); }
    MM(1); BAR();
    // P3: read A-q2; stage kt(2i+2).U2 {B2,A0} (A-q0 free since P1)
    RDA(0, 2);
    if (st) { STG_B(k2, 2); STG_A(k2, 0); }
    MM(2); BAR();
    // P4: read A-q3; stage kt(2i+2).U3 {A1,A2}; vmcnt(6) completes kt(2i+1)
    RDA(0, 3);
    if (st) { STG_A(k2, 1); STG_A(k2, 2); }
    MM(3);
    if (st) asm volatile("s_waitcnt vmcnt(6)" ::: "memory");
    else    asm volatile("s_waitcnt vmcnt(0)" ::: "memory");
    BAR();
    // P5: read kt(2i+1) {A-q0, B-all} from dbuf1; stage kt(2i+2).U4 (A3 free since P4)
    RDA(1, 0); RDB(1);
    if (st) STG_A(k2, 3);
    MM(0); BAR();
    // P6: read A-q1; stage kt(2i+3).U1 (dbuf1 B free since P5)
    RDA(1, 1);
    if (st) { STG_B(k3, 0); STG_B(k3, 1); }
    MM(1); BAR();
    // P7: read A-q2; stage kt(2i+3).U2
    RDA(1, 2);
    if (st) { STG_B(k3, 2); STG_A(k3, 0); }
    MM(2); BAR();
    // P8: read A-q3; stage kt(2i+3).U3; vmcnt(6) completes kt(2i+2)
    RDA(1, 3);
    if (st) { STG_A(k3, 1); STG_A(k3, 2); }
    MM(3);
    if (st) asm volatile("s_waitcnt vmcnt(6)" ::: "memory");
    else    asm volatile("s_waitcnt vmcnt(0)" ::: "memory");
    BAR();
  }

#undef STG_A
#undef STG_B
#undef RDA
#undef RDB
#undef MM
#undef BAR

  // epilogue: per 16-col fragment select Q/K/V target (fragments never straddle 2048)
#pragma unroll
  for (int n = 0; n < 3; ++n) {
    int col = tn + wc * 48 + n * 16 + c;
    int sel = col >> 11;
    if (sel < 2) {
      float* outp = sel ? kpre : qpre;
      const float* bias = sel ? bk : bq;
      int col2 = col & 2047;
      float bvv = bias[col2];
#pragma unroll
      for (int m = 0; m < 8; ++m) {
        int row0 = tm + wr * 128 + m * 16 + g * 4;
#pragma unroll
        for (int i = 0; i < 4; ++i)
          outp[(size_t)(row0 + i) * 2048 + col2] = acc[m][n][i] + bvv;
      }
    } else {
      int colv = col - 4096;
      float bvv = bv[colv];
#pragma unroll
      for (int m = 0; m < 8; ++m) {
        int row0 = tm + wr * 128 + m * 16 + g * 4;
        uint2 o;
        o.x = pack2(acc[m][n][0] + bvv, acc[m][n][1] + bvv);
        o.y = pack2(acc[m][n][2] + bvv, acc[m][n][3] + bvv);
        *(uint2*)(Vt + (size_t)colv * S_ + row0) = o;
      }
    }
  }
}

// ---------------- Wo GEMM split-K=2, 8 waves, dbuf + counted vmcnt (R8) ----------------
__global__ __launch_bounds__(512) void gemm_wo_db(const ushort* __restrict__ A,
                                                  const ushort* __restrict__ B,
                                                  float* __restrict__ pbuf, int K) {
  __shared__ __align__(16) unsigned char As[16384];
  __shared__ __align__(16) unsigned char Bs[16384];
  const int t = threadIdx.x, l = t & 63, w = t >> 6;
  const int g = l >> 4, c = l & 15;
  const int wr = w >> 1, wc = w & 1;
  const int tm = blockIdx.y * 128, tn = blockIdx.x * 128;
  const int ks = blockIdx.z;
  const int k0 = ks * (K >> 1);

  const int srow = w * 16 + (l >> 2);
  const int schunk = (l & 3) ^ (srow & 3);
  const ushort* Ag = A + (size_t)(tm + srow) * K + k0 + schunk * 8;
  const ushort* Bg = B + (size_t)(tn + srow) * K + k0 + schunk * 8;

  f32x4 acc[2][4] = {};

  const int NT = K >> 6;   // (K/2)/32 = 32 K-steps
  gload_lds16(Ag, As + w * 1024);
  gload_lds16(Bg, Bs + w * 1024);

  for (int j = 0; j < NT; ++j) {
    const int buf = j & 1, nb = buf ^ 1;
    if (j + 1 < NT) {
      const int kt1 = (j + 1) << 5;
      gload_lds16(Ag + kt1, As + nb * 8192 + w * 1024);
      gload_lds16(Bg + kt1, Bs + nb * 8192 + w * 1024);
      asm volatile("s_waitcnt vmcnt(2)" ::: "memory");
    } else {
      asm volatile("s_waitcnt vmcnt(0)" ::: "memory");
    }
    __builtin_amdgcn_s_barrier();

    const unsigned char* Ab = As + buf * 8192;
    const unsigned char* Bb = Bs + buf * 8192;
    bf16x8 af[2], bfr[4];
#pragma unroll
    for (int m = 0; m < 2; ++m) {
      int row = wr * 32 + m * 16 + c;
      af[m] = *(const bf16x8*)(Ab + row * 64 + ((g ^ (row & 3)) << 4));
    }
#pragma unroll
    for (int n = 0; n < 4; ++n) {
      int row = wc * 64 + n * 16 + c;
      bfr[n] = *(const bf16x8*)(Bb + row * 64 + ((g ^ (row & 3)) << 4));
    }
#pragma unroll
    for (int m = 0; m < 2; ++m)
#pragma unroll
      for (int n = 0; n < 4; ++n)
        acc[m][n] = __builtin_amdgcn_mfma_f32_16x16x32_bf16(af[m], bfr[n], acc[m][n], 0, 0, 0);

    __builtin_amdgcn_s_barrier();
  }

  float* out = pbuf + (size_t)ks * 2048 * 2048;
#pragma unroll
  for (int n = 0; n < 4; ++n) {
    int col = tn + wc * 64 + n * 16 + c;
#pragma unroll
    for (int m = 0; m < 2; ++m) {
      int row0 = tm + wr * 32 + m * 16 + g * 4;
#pragma unroll
      for (int i = 0; i < 4; ++i)
        out[(size_t)(row0 + i) * 2048 + col] = acc[m][n][i];
    }
  }
}

__global__ __launch_bounds__(256) void reduce_wo(const float* __restrict__ p,
                                                 const float* __restrict__ bo,
                                                 float* __restrict__ out, int n4) {
  int i = blockIdx.x * blockDim.x + threadIdx.x;
  if (i >= n4) return;
  float4 a = ((const float4*)p)[i];
  float4 b = ((const float4*)p)[i + n4];
  float4 bb = *(const float4*)(bo + ((i * 4) & 2047));
  float4 o;
  o.x = a.x + b.x + bb.x; o.y = a.y + b.y + bb.y;
  o.z = a.z + b.z + bb.z; o.w = a.w + b.w + bb.w;
  ((float4*)out)[i] = o;
}

// ---------------- fused rmsnorm + 3-axis RoPE + scale-fold, fp32 -> bf16 ----------------
__global__ __launch_bounds__(256) void fuse_rms_rope(const float* __restrict__ qpre,
                                                     const float* __restrict__ kpre,
                                                     const float* __restrict__ gq,
                                                     const float* __restrict__ gk,
                                                     const float* __restrict__ fc,
                                                     const float* __restrict__ fs,
                                                     const int* __restrict__ pH,
                                                     const int* __restrict__ pW,
                                                     ushort* __restrict__ Qb,
                                                     ushort* __restrict__ Kb,
                                                     int dim, float foldq) {
  const int which = blockIdx.y;
  const float* pre = which ? kpre : qpre;
  const float* gw = which ? gk : gq;
  ushort* outp = which ? Kb : Qb;
  const float fold = which ? 1.0f : foldq;

  const int p = blockIdx.x, t = threadIdx.x;
  const float* row = pre + (size_t)p * dim;
  float v[8];
  {
    float4 a = *(const float4*)(row + t * 8);
    float4 b = *(const float4*)(row + t * 8 + 4);
    v[0] = a.x; v[1] = a.y; v[2] = a.z; v[3] = a.w;
    v[4] = b.x; v[5] = b.y; v[6] = b.z; v[7] = b.w;
  }
  float ss = 0.f;
#pragma unroll
  for (int i = 0; i < 8; ++i) ss += v[i] * v[i];
#pragma unroll
  for (int off = 32; off; off >>= 1) ss += __shfl_xor(ss, off);
  __shared__ float wsum[4];
  if ((t & 63) == 0) wsum[t >> 6] = ss;
  __syncthreads();
  float rstd = rsqrtf((wsum[0] + wsum[1] + wsum[2] + wsum[3]) * (1.0f / dim) + 1e-6f);
  float gv[8];
  {
    float4 a = *(const float4*)(gw + t * 8);
    float4 b = *(const float4*)(gw + t * 8 + 4);
    gv[0] = a.x; gv[1] = a.y; gv[2] = a.z; gv[3] = a.w;
    gv[4] = b.x; gv[5] = b.y; gv[6] = b.z; gv[7] = b.w;
  }
#pragma unroll
  for (int i = 0; i < 8; ++i) v[i] = v[i] * rstd * gv[i];

  const int H = pH[0], W = pW[0];
  const int hw = H * W;
  const int fr = p / hw;
  const int rem = p - fr * hw;
  const int hh = rem / W;
  const int ww = rem - hh * W;
  const int hd = dim / 16;
  const int cd = hd >> 1;
  const int c2 = cd / 3, c1 = cd - 2 * c2;
  const int j0 = ((t * 8) % hd) >> 1;

  uint ob[4];
#pragma unroll
  for (int q = 0; q < 4; ++q) {
    int j = j0 + q;
    int ri = (j < c1) ? fr : ((j < c1 + c2) ? hh : ww);
    float cs = fc[ri * cd + j];
    float sn = fs[ri * cd + j];
    float a = v[2 * q], b = v[2 * q + 1];
    ob[q] = pack2((a * cs - b * sn) * fold, (a * sn + b * cs) * fold);
  }
  uint4 o4; o4.x = ob[0]; o4.y = ob[1]; o4.z = ob[2]; o4.w = ob[3];
  *(uint4*)(outp + (size_t)p * dim + t * 8) = o4;
}

// ---------------- flash attention, 32x32 MFMA, 4 q-subtiles x 2 KV-splits ----------------
__global__ __launch_bounds__(512, 2) void attn32(const ushort* __restrict__ Qb,
                                                 const ushort* __restrict__ Kb,
                                                 const ushort* __restrict__ Vt,
                                                 ushort* __restrict__ Ob,
                                                 const int* __restrict__ seq_lens,
                                                 int S_, int DIMc) {
  __shared__ __align__(16) unsigned char smem[66560];
  float* mlbuf = (float*)(smem + 65536);
  const int t = threadIdx.x, l = t & 63, w = t >> 6;
  const int qsub = w & 3, ksp = w >> 2;
  const int h = l >> 5, ql = l & 31;

  const int orig = blockIdx.y * gridDim.x + blockIdx.x;
  const int nwg = gridDim.x * gridDim.y;
  const int lin = (orig & 7) * (nwg >> 3) + (orig >> 3);
  const int q0 = (lin % gridDim.x) * 128;
  const int head = lin / gridDim.x;
  const int kvlen = seq_lens[0];

  unsigned char* sk_s = smem + ksp * 16384;
  unsigned char* sv_s = smem + 32768 + ksp * 16384;

  bf16x8 qf[8];
  {
    const ushort* qp = Qb + (size_t)(q0 + qsub * 32 + ql) * DIMc + head * 128 + h * 8;
#pragma unroll
    for (int s = 0; s < 8; ++s) qf[s] = *(const bf16x8*)(qp + s * 16);
  }

  f32x16 ofr[4] = {};
  float m_run = -1e30f, l_run = 0.f;

  const int nt = (kvlen + 63) >> 6;
  const int half = (nt + 1) >> 1;
  const int tbase = ksp ? half : 0;
  const int mycnt = ksp ? (nt - half) : half;

  for (int tt = 0; tt < half; ++tt) {
    __syncthreads();
    if (tt < mycnt) {
      const int kv0 = (tbase + tt) * 64;
#pragma unroll
      for (int it = 0; it < 4; ++it) {
        int kr = qsub * 16 + it * 4 + (l >> 4);
        int kc = (l & 15) ^ (kr & 15);
        gload_lds16(Kb + (size_t)(kv0 + kr) * DIMc + head * 128 + kc * 8,
                    sk_s + qsub * 4096 + it * 1024);
        int vr = qsub * 32 + it * 8 + (l >> 3);
        int vc = (l & 7) ^ (vr & 7);
        gload_lds16(Vt + (size_t)(head * 128 + vr) * S_ + kv0 + vc * 8,
                    sv_s + qsub * 4096 + it * 1024);
      }
    }
    __syncthreads();
    if (tt >= mycnt) continue;
    const int kv0 = (tbase + tt) * 64;

    f32x16 sfr[2] = {};
    __builtin_amdgcn_s_setprio(1);
#pragma unroll
    for (int kb = 0; kb < 2; ++kb) {
      const unsigned char* kbp = sk_s + (kb * 32 + ql) * 256;
      const int rx = (kb * 32 + ql) & 15;
#pragma unroll
      for (int s = 0; s < 8; ++s) {
        bf16x8 kf = *(const bf16x8*)(kbp + (((s * 2 + h) ^ rx) << 4));
        sfr[kb] = __builtin_amdgcn_mfma_f32_32x32x16_bf16(kf, qf[s], sfr[kb], 0, 0, 0);
      }
    }
    __builtin_amdgcn_s_setprio(0);

    if (kv0 + 64 > kvlen) {
#pragma unroll
      for (int kb = 0; kb < 2; ++kb)
#pragma unroll
        for (int r = 0; r < 16; ++r) {
          int key = kv0 + kb * 32 + (r & 3) + 8 * (r >> 2) + 4 * h;
          if (key >= kvlen) sfr[kb][r] = -1e30f;
        }
    }

    float mt = -1e30f;
#pragma unroll
    for (int kb = 0; kb < 2; ++kb)
#pragma unroll
      for (int r = 0; r < 16; ++r) mt = fmaxf(mt, sfr[kb][r]);
    mt = fmaxf(mt, __shfl_xor(mt, 32));

    if (!__all(mt <= m_run + 8.0f)) {
      float m_new = fmaxf(m_run, mt);
      float fac = __builtin_amdgcn_exp2f(m_run - m_new);
      l_run *= fac;
#pragma unroll
      for (int df = 0; df < 4; ++df) ofr[df] *= fac;
      m_run = m_new;
    }

    float ls = 0.f;
    uint u[2][4][2];
#pragma unroll
    for (int kb = 0; kb < 2; ++kb)
#pragma unroll
      for (int G = 0; G < 4; ++G) {
        float p0 = __builtin_amdgcn_exp2f(sfr[kb][G * 4 + 0] - m_run);
        float p1 = __builtin_amdgcn_exp2f(sfr[kb][G * 4 + 1] - m_run);
        float p2 = __builtin_amdgcn_exp2f(sfr[kb][G * 4 + 2] - m_run);
        float p3 = __builtin_amdgcn_exp2f(sfr[kb][G * 4 + 3] - m_run);
        ls += (p0 + p1) + (p2 + p3);
        u[kb][G][0] = cvt_pk_bf16(p0, p1);
        u[kb][G][1] = cvt_pk_bf16(p2, p3);
      }
    ls += __shfl_xor(ls, 32);
    l_run += ls;

#pragma unroll
    for (int ks = 0; ks < 4; ++ks) {
      const int kb = ks >> 1, G0 = (ks & 1) * 2;
      uint own0 = h ? u[kb][G0 + 1][0] : u[kb][G0][0];
      uint own1 = h ? u[kb][G0 + 1][1] : u[kb][G0][1];
      uint snd0 = h ? u[kb][G0][0] : u[kb][G0 + 1][0];
      uint snd1 = h ? u[kb][G0][1] : u[kb][G0 + 1][1];
      uint rcv0 = __shfl_xor(snd0, 32);
      uint rcv1 = __shfl_xor(snd1, 32);
      union { uint4 q; bf16x8 b; } uu;
      uu.q.x = h ? rcv0 : own0;
      uu.q.y = h ? rcv1 : own1;
      uu.q.z = h ? own0 : rcv0;
      uu.q.w = h ? own1 : rcv1;
      __builtin_amdgcn_s_setprio(1);
#pragma unroll
      for (int df = 0; df < 4; ++df) {
        const int row = df * 32 + ql;
        bf16x8 vf = *(const bf16x8*)(sv_s + row * 128 + (((ks * 2 + h) ^ (row & 7)) << 4));
        ofr[df] = __builtin_amdgcn_mfma_f32_32x32x16_bf16(vf, uu.b, ofr[df], 0, 0, 0);
      }
      __builtin_amdgcn_s_setprio(0);
    }
  }

  __syncthreads();
  if (ksp == 1) {
    if (h == 0) { mlbuf[qsub * 64 + ql] = m_run; mlbuf[qsub * 64 + 32 + ql] = l_run; }
    float* ob = (float*)(smem + qsub * 16384);
#pragma unroll
    for (int df = 0; df < 4; ++df)
#pragma unroll
      for (int r = 0; r < 16; ++r) {
        int d = df * 32 + (r & 3) + 8 * (r >> 2) + 4 * h;
        ob[d * 32 + ql] = ofr[df][r];
      }
  }
  __syncthreads();
  if (ksp == 0) {
    float m2 = mlbuf[qsub * 64 + ql], l2 = mlbuf[qsub * 64 + 32 + ql];
    float mstar = fmaxf(m_run, m2);
    float f1 = __builtin_amdgcn_exp2f(m_run - mstar);
    float f2 = (l2 > 0.f) ? __builtin_amdgcn_exp2f(m2 - mstar) : 0.f;
    float lstar = l_run * f1 + l2 * f2;
    float inv = 1.0f / lstar;
    float a1 = f1 * inv, a2 = f2 * inv;
    const float* ob = (const float*)(smem + qsub * 16384);
    ushort* orow = Ob + (size_t)(q0 + qsub * 32 + ql) * DIMc + head * 128;
#pragma unroll
    for (int df = 0; df < 4; ++df)
#pragma unroll
      for (int G = 0; G < 4; ++G) {
        int d0 = df * 32 + 8 * G + 4 * h;
        float v0 = ofr[df][G * 4 + 0] * a1 + ob[(d0 + 0) * 32 + ql] * a2;
        float v1 = ofr[df][G * 4 + 1] * a1 + ob[(d0 + 1) * 32 + ql] * a2;
        float v2 = ofr[df][G * 4 + 2] * a1 + ob[(d0 + 2) * 32 + ql] * a2;
        float v3 = ofr[df][G * 4 + 3] * a1 + ob[(d0 + 3) * 32 + ql] * a2;
        uint2 o; o.x = pack2(v0, v1); o.y = pack2(v2, v3);
        *(uint2*)(orow + d0) = o;
      }
  }
}

// ---------------- host ----------------
extern "C" void kernel_launch(void* const* d_in, const int* in_sizes, int n_in,
                              void* d_out, int out_size, void* d_ws, size_t ws_size,
                              hipStream_t stream) {
  const float* x  = (const float*)d_in[0];
  const float* fc = (const float*)d_in[1];
  const float* fs = (const float*)d_in[2];
  const float* Wq = (const float*)d_in[3];
  const float* bq = (const float*)d_in[4];
  const float* Wk = (const float*)d_in[5];
  const float* bk = (const float*)d_in[6];
  const float* Wv = (const float*)d_in[7];
  const float* bv = (const float*)d_in[8];
  const float* Wo = (const float*)d_in[9];
  const float* bo = (const float*)d_in[10];
  const float* gq = (const float*)d_in[11];
  const float* gk = (const float*)d_in[12];
  const int* seq  = (const int*)d_in[13];
  const int* pH   = (const int*)d_in[15];
  const int* pW   = (const int*)d_in[16];

  const int DIMc = in_sizes[4];          // 2048
  const int S_   = in_sizes[0] / DIMc;   // 2048

  char* ws = (char*)d_ws;
  const size_t MB = 1024ull * 1024ull;
  ushort* xb    = (ushort*)(ws + 0 * MB);
  ushort* Wqkvb = (ushort*)(ws + 8 * MB);    // [6144][2048] bf16 = 24 MB
  ushort* Wob   = (ushort*)(ws + 32 * MB);
  float*  qpre  = (float*)(ws + 40 * MB);    // 16 MB
  float*  kpre  = (float*)(ws + 56 * MB);    // 16 MB
  ushort* Qb    = (ushort*)(ws + 72 * MB);
  ushort* Kb    = (ushort*)(ws + 80 * MB);
  ushort* Vt    = (ushort*)(ws + 88 * MB);
  ushort* Ob    = (ushort*)(ws + 40 * MB);   // aliases qpre (dead after fuse)
  float*  pbuf  = (float*)(ws + 56 * MB);    // 32 MB, aliases kpre/Qb/Kb (dead by then)

  const int nx8 = (S_ * DIMc) / 8;
  const int nw8 = (DIMc * DIMc) / 8;
  const int nmax = (nx8 > nw8 ? nx8 : nw8);
  cvt5<<<dim3((nmax + 255) / 256, 5), 256, 0, stream>>>(x, Wq, Wk, Wv, Wo,
                                                        xb, Wqkvb, Wob, nx8, nw8);

  gemm_qkv192<<<dim3(3 * DIMc / 192, S_ / 256), 512, 0, stream>>>(
      xb, Wqkvb, bq, bk, bv, qpre, kpre, Vt, DIMc, S_);

  const float foldq = LOG2E / sqrtf((float)(DIMc / 16));
  fuse_rms_rope<<<dim3(S_, 2), 256, 0, stream>>>(qpre, kpre, gq, gk, fc, fs, pH, pW,
                                                 Qb, Kb, DIMc, foldq);

  attn32<<<dim3(S_ / 128, 16), 512, 0, stream>>>(Qb, Kb, Vt, Ob, seq, S_, DIMc);

  gemm_wo_db<<<dim3(16, 16, 2), 512, 0, stream>>>(Ob, Wob, pbuf, DIMc);
  reduce_wo<<<(S_ * DIMc / 4 + 255) / 256, 256, 0, stream>>>(pbuf, bo, (float*)d_out,
                                                             S_ * DIMc / 4);
}